// Round 9
// baseline (147.484 us; speedup 1.0000x reference)
//
#include <hip/hip_runtime.h>
#include <math.h>

#define NB 4
#define HH 96
#define WW 96
#define HW (HH*WW)
#define NPIX (NB*HW)
#define C_IN 128
#define C_OUT 64
#define DGRP 16
#define CG 8

typedef short v8s __attribute__((ext_vector_type(8)));
typedef float v4f __attribute__((ext_vector_type(4)));
typedef _Float16 f16x2 __attribute__((ext_vector_type(2)));
typedef _Float16 f16x8 __attribute__((ext_vector_type(8)));
typedef unsigned short u16;
typedef unsigned int u32;

__device__ __forceinline__ u16 f2bf(float x) {
    u32 u = __float_as_uint(x);
    u32 r = (u + 0x7FFFu + ((u >> 16) & 1u)) >> 16;   // RNE
    return (u16)r;
}
__device__ __forceinline__ float ftanh(float x) {
    float e = __expf(2.0f * x);
    return 1.0f - 2.0f / (e + 1.0f);
}
__device__ __forceinline__ float fsigm(float x) {
    return 1.0f / (1.0f + __expf(-x));
}
// fp32 pair -> packed fp16 (RTZ), 1 VALU op (inline asm: builtin's __fp16
// vector return type clashes with _Float16 typedefs on this toolchain)
__device__ __forceinline__ u32 pkrtz(float a, float b) {
    u32 r;
    asm("v_cvt_pkrtz_f16_f32 %0, %1, %2" : "=v"(r) : "v"(a), "v"(b));
    return r;
}
__device__ __forceinline__ f16x2 u2h(u32 u) { union { u32 u; f16x2 h; } c; c.u = u; return c.h; }
__device__ __forceinline__ u32 h2u(f16x2 h) { union { f16x2 h; u32 u; } c; c.h = h; return c.u; }
__device__ __forceinline__ f16x8 q2h8(uint4 q) { union { uint4 q; f16x8 h; } c; c.q = q; return c.h; }
// fp32 -> fp16 (RNE) low 16 bits
__device__ __forceinline__ u16 f16of(float a) {
    u32 r;
    asm("v_cvt_f16_f32 %0, %1" : "=v"(r) : "v"(a));
    return (u16)r;
}
// fp16 (low 16 of w) -> fp32
__device__ __forceinline__ float f16lo(u32 w) {
    float r;
    asm("v_cvt_f32_f16 %0, %1" : "=v"(r) : "v"(w));
    return r;
}
__device__ __forceinline__ float f16hi(u32 w) { return f16lo(w >> 16); }

// ---------------------------------------------------------------------------
// Prep 1: concat(extra_feat, flow1, flow2) -> pixel-major bf16 [NPIX][256]
// (conv stack stays bf16)
// ---------------------------------------------------------------------------
__global__ __launch_bounds__(256) void prep_catT(
    const float* __restrict__ ef, const float* __restrict__ f1,
    const float* __restrict__ f2, u16* __restrict__ catT)
{
    __shared__ float T[64][65];
    const int t   = threadIdx.x;
    const int p   = blockIdx.x * 64;
    const int ch0 = blockIdx.y * 64;
    const int n   = p / HW;
    const int rem = p - n * HW;
    const int px  = t & 63;
    const int wv  = t >> 6;
    #pragma unroll
    for (int kk = 0; kk < 16; ++kk) {
        int chl = wv * 16 + kk;
        int ch  = ch0 + chl;
        float v = 0.f;
        if (ch < 192)      v = ef[(size_t)(n * 192 + ch) * HW + rem + px];
        else if (ch < 194) v = f1[(size_t)(n * 2 + (ch - 192)) * HW + rem + px];
        else if (ch < 196) v = f2[(size_t)(n * 2 + (ch - 194)) * HW + rem + px];
        T[chl][px] = v;
    }
    __syncthreads();
    const int s = t & 7;
    #pragma unroll
    for (int it = 0; it < 2; ++it) {
        int pxo = (t >> 3) + it * 32;
        u32 w0 = (u32)f2bf(T[s*8+0][pxo]) | ((u32)f2bf(T[s*8+1][pxo]) << 16);
        u32 w1 = (u32)f2bf(T[s*8+2][pxo]) | ((u32)f2bf(T[s*8+3][pxo]) << 16);
        u32 w2 = (u32)f2bf(T[s*8+4][pxo]) | ((u32)f2bf(T[s*8+5][pxo]) << 16);
        u32 w3 = (u32)f2bf(T[s*8+6][pxo]) | ((u32)f2bf(T[s*8+7][pxo]) << 16);
        *(uint4*)&catT[((size_t)(p + pxo)) * 256 + ch0 + s * 8] = make_uint4(w0, w1, w2, w3);
    }
}

// ---------------------------------------------------------------------------
// Prep: x [N,128,H,W] fp32 -> xT group-major FP16 [16 groups][NPIX][8]
// (fp16 instead of bf16 -- feeds the fp16 pk-blend + f16 MFMA; x~N(0,1)
// is well within fp16 range, and fp16 2^-11 beats bf16 2^-8.)
// ---------------------------------------------------------------------------
__global__ __launch_bounds__(256) void prep_xT(
    const float* __restrict__ x, u16* __restrict__ xT)
{
    __shared__ float T[64][65];
    const int t   = threadIdx.x;
    const int p   = blockIdx.x * 64;
    const int ch0 = blockIdx.y * 64;
    const int n   = p / HW;
    const int rem = p - n * HW;
    const int px  = t & 63;
    const int wv  = t >> 6;
    #pragma unroll
    for (int kk = 0; kk < 16; ++kk) {
        int chl = wv * 16 + kk;
        T[chl][px] = x[(size_t)(n * C_IN + ch0 + chl) * HW + rem + px];
    }
    __syncthreads();
    const int s = t & 7;
    #pragma unroll
    for (int it = 0; it < 2; ++it) {
        int pxo = (t >> 3) + it * 32;
        u32 w0 = pkrtz(T[s*8+0][pxo], T[s*8+1][pxo]);
        u32 w1 = pkrtz(T[s*8+2][pxo], T[s*8+3][pxo]);
        u32 w2 = pkrtz(T[s*8+4][pxo], T[s*8+5][pxo]);
        u32 w3 = pkrtz(T[s*8+6][pxo], T[s*8+7][pxo]);
        *(uint4*)&xT[((size_t)(ch0 / 8 + s) * NPIX + (p + pxo)) * 8] = make_uint4(w0, w1, w2, w3);
    }
}

// ---------------------------------------------------------------------------
// ONE fused weight-pack kernel. conv weights -> bf16 fragment-major;
// dcn weights -> FP16 fragment-major [kk=36][m=4][lane=64][c=8].
// ---------------------------------------------------------------------------
__device__ __forceinline__ void pack_wf_one(
    const float* __restrict__ w, u16* __restrict__ wp,
    int Cout, int CoutPad, int CIN, int CIP, int idx)
{
    const int NKF = CIP / 32, NOG = CoutPad / 16;
    int c    = idx & 7;
    int ln   = (idx >> 3) & 63;
    int rest = idx >> 9;
    int og   = rest % NOG; rest /= NOG;
    int kfg  = rest % NKF;
    int tap  = rest / NKF;
    int l15 = ln & 15, lg = ln >> 4;
    int o  = og * 16 + l15;
    int ci = kfg * 32 + lg * 8 + c;
    float v = (o < Cout && ci < CIN) ? w[((size_t)o * CIN + ci) * 9 + tap] : 0.f;
    wp[idx] = f2bf(v);
}

__global__ __launch_bounds__(256) void pack_all(
    const float* __restrict__ w0, u16* __restrict__ w0p,
    const float* __restrict__ w1, u16* __restrict__ w1p,
    const float* __restrict__ w2, u16* __restrict__ w2p,
    const float* __restrict__ w3, u16* __restrict__ w3p,
    const float* __restrict__ wd, u16* __restrict__ wdf)
{
    int idx = blockIdx.x * 256 + threadIdx.x;
    if (idx < 147456) { pack_wf_one(w0, w0p, 64, 64, 196, 256, idx); return; }
    idx -= 147456;
    if (idx < 36864)  { pack_wf_one(w1, w1p, 64, 64, 64, 64, idx); return; }
    idx -= 36864;
    if (idx < 36864)  { pack_wf_one(w2, w2p, 64, 64, 64, 64, idx); return; }
    idx -= 36864;
    if (idx < 258048) { pack_wf_one(w3, w3p, 432, 448, 64, 64, idx); return; }
    idx -= 258048;
    {   // pack_wdf (fp16)
        int c  = idx & 7;
        int ln = (idx >> 3) & 63;
        int m  = (idx >> 9) & 3;
        int kk = idx >> 11;
        int l15 = ln & 15, lg = ln >> 4;
        int o = m * 16 + l15;
        int slot = kk * 4 + lg;
        int g = slot / 9, kt = slot - 9 * g;
        wdf[idx] = f16of(wd[((size_t)(o * C_IN + g * CG + c)) * 9 + kt]);
    }
}

// ---------------------------------------------------------------------------
// MFMA implicit-GEMM 3x3 conv, 256 thr = 4 waves. Fragment-major weights.
// conv3 (NOB>1) epilogue applies 10*tanh (fp16 pairs via pkrtz) and
// sigmoid (fp16) -- keeps transcendentals out of the issue-bound dcn.
// ---------------------------------------------------------------------------
template<int CIP, int NCHUNK, int OST, bool LRELU, bool TOUT, int NOB>
__global__ __launch_bounds__(256) void conv_mfma(
    const u16* __restrict__ inT,
    const u16* __restrict__ wp,
    const float* __restrict__ bias,
    int CoutReal,
    u16* __restrict__ outT,
    u32* __restrict__ pairT,
    u16* __restrict__ maskT)
{
    constexpr int COLS  = (NOB > 1) ? 100 : 50;        // padded row stride
    constexpr int LTILE = 3 * COLS * 64;
    constexpr int LSZ   = (NCHUNK > 1) ? 2 * LTILE : LTILE;
    constexpr int NKF   = CIP / 32;
    constexpr int NOG   = OST / 16;
    __shared__ __align__(16) u16 L[LSZ];

    const int t   = threadIdx.x;
    const int tb  = blockIdx.x;
    const int row = (NOB > 1) ? tb : (tb >> 1);
    const int p0  = (NOB > 1) ? 0 : (tb & 1) * 48;
    const int n   = row / HH;
    const int h   = row - n * HH;
    const int ln  = t & 63;
    const int wv  = t >> 6;          // 0..3
    const int l15 = ln & 15;
    const int lg  = ln >> 4;

    auto stage = [&](int ch, int buf) {
        const int cb = ch * 64;
        const int NCOL = (NOB > 1) ? 98 : 50;
        const int NTASK = 3 * NCOL * 8;
        u16* Lb = &L[buf * LTILE];
        #pragma unroll
        for (int it = 0; it < (NTASK + 255) / 256; ++it) {
            int task = it * 256 + t;
            if (task < NTASK) {
                int s  = task & 7;
                int cl = task >> 3;
                int r3 = cl / NCOL;
                int c  = cl - r3 * NCOL;
                int yy = h + r3 - 1;
                int xx = p0 + c - 1;
                uint4 v = make_uint4(0u, 0u, 0u, 0u);
                if ((unsigned)yy < HH && (unsigned)xx < WW)
                    v = *(const uint4*)&inT[((size_t)(n * HW + yy * WW + xx)) * CIP + cb + s * 8];
                *(uint4*)&Lb[(r3 * COLS + c) * 64 + ((s ^ (c & 7)) * 8)] = v;
            }
        }
    };

    if constexpr (NOB == 1) {
        v4f acc[3];
        #pragma unroll
        for (int i = 0; i < 3; ++i) acc[i] = (v4f){0.f, 0.f, 0.f, 0.f};

        stage(0, 0);
        for (int ch = 0; ch < NCHUNK; ++ch) {
            __syncthreads();
            if (ch + 1 < NCHUNK) stage(ch + 1, (ch + 1) & 1);
            const u16* Lb = &L[(ch & 1) * LTILE];
            #pragma unroll
            for (int tap = 0; tap < 9; ++tap) {
                const int ty = tap / 3, tx = tap - ty * 3;
                #pragma unroll
                for (int kf = 0; kf < 2; ++kf) {
                    v8s b = *(const v8s*)&wp[((((size_t)tap * NKF + (ch * 2 + kf)) * NOG + wv) * 64 + ln) * 8];
                    #pragma unroll
                    for (int fm = 0; fm < 3; ++fm) {
                        int c = fm * 16 + l15 + tx;
                        v8s a = *(const v8s*)&Lb[(ty * COLS + c) * 64 + (((kf * 4 + lg) ^ (c & 7)) * 8)];
                        acc[fm] = __builtin_amdgcn_mfma_f32_16x16x32_bf16(a, b, acc[fm], 0, 0, 0);
                    }
                }
            }
        }

        int o = wv * 16 + l15;
        float bv = (o < CoutReal) ? bias[o] : 0.f;
        #pragma unroll
        for (int fm = 0; fm < 3; ++fm) {
            #pragma unroll
            for (int r = 0; r < 4; ++r) {
                int px = p0 + fm * 16 + lg * 4 + r;
                float v = acc[fm][r] + bv;
                if (LRELU) v = (v >= 0.f) ? v : 0.1f * v;
                outT[((size_t)(n * HW + h * WW + px)) * OST + o] = f2bf(v);
            }
        }
    } else {
        stage(0, 0);
        __syncthreads();
        const size_t gpix = (size_t)n * HW + h * WW;
        const int ob_lo = blockIdx.y * 4;
        const int ob_hi = (ob_lo + 4 < NOB) ? ob_lo + 4 : NOB;

        for (int ob = ob_lo; ob < ob_hi; ++ob) {
            const int obase = ob * 64 + wv * 16;
            if (obase >= 432) continue;

            v4f acc[6];
            #pragma unroll
            for (int i = 0; i < 6; ++i) acc[i] = (v4f){0.f, 0.f, 0.f, 0.f};

            #pragma unroll
            for (int tap = 0; tap < 9; ++tap) {
                const int ty = tap / 3, tx = tap - ty * 3;
                #pragma unroll
                for (int kf = 0; kf < 2; ++kf) {
                    v8s bw = *(const v8s*)&wp[((((size_t)tap * NKF + kf) * NOG + (ob * 4 + wv)) * 64 + ln) * 8];
                    #pragma unroll
                    for (int fm = 0; fm < 6; ++fm) {
                        int c = fm * 16 + l15 + tx;
                        v8s a = *(const v8s*)&L[(ty * COLS + c) * 64 + (((kf * 4 + lg) ^ (c & 7)) * 8)];
                        acc[fm] = __builtin_amdgcn_mfma_f32_16x16x32_bf16(bw, a, acc[fm], 0, 0, 0);
                    }
                }
            }

            float bv[4];
            #pragma unroll
            for (int r = 0; r < 4; ++r) bv[r] = bias[obase + lg * 4 + r];

            if (obase < 288) {
                // offset channels: 10*tanh on fp32 acc, ONE pkrtz per pair
                const int pr = (obase + lg * 4) >> 1;
                #pragma unroll
                for (int fm = 0; fm < 6; ++fm) {
                    const size_t pix = gpix + fm * 16 + l15;
                    u32 v0 = pkrtz(10.0f * ftanh(acc[fm][0] + bv[0]),
                                   10.0f * ftanh(acc[fm][1] + bv[1]));
                    u32 v1 = pkrtz(10.0f * ftanh(acc[fm][2] + bv[2]),
                                   10.0f * ftanh(acc[fm][3] + bv[3]));
                    pairT[(size_t)pr * NPIX + pix]       = v0;
                    pairT[(size_t)(pr + 1) * NPIX + pix] = v1;
                }
            } else {
                // mask channels: sigmoid, fp16
                #pragma unroll
                for (int fm = 0; fm < 6; ++fm) {
                    const size_t pix = gpix + fm * 16 + l15;
                    #pragma unroll
                    for (int r = 0; r < 4; ++r) {
                        int mch = obase + lg * 4 + r - 288;
                        maskT[(size_t)mch * NPIX + pix] = f16of(fsigm(acc[fm][r] + bv[r]));
                    }
                }
            }
        }
    }
}

// ---------------------------------------------------------------------------
// Fused DCN sample+GEMM, K-split x3, 2-deep pipeline + XCD swizzle (proven).
//  (a) NON-TEMPORAL loads for pairT/maskT and nt stores for part: stops
//      ~60MB of one-shot stream traffic from thrashing the per-XCD L2, so
//      the xT window (~1.2MB/XCD) stays resident and gathers become L2 hits
//      (~200cy, coverable by the 2-deep pipeline) instead of HBM (~900cy).
//  (b) packed-fp16 blend: 4x v_pk_fma_f16 per word (was 8 fma + cvtpk);
//      MFMA -> 16x16x32_f16 (same rate as bf16). blend 36->20 VALU
//      ops/sample; precision improves (fp16 2^-11 chain vs bf16 2^-8).
// ---------------------------------------------------------------------------
__global__ __launch_bounds__(256) void dcn_fused(
    const u16* __restrict__ xT,     // [16][NPIX][8] fp16
    const float* __restrict__ f1,
    const float* __restrict__ f2,
    const u32*  __restrict__ pairT, // [144][NPIX] fp16 pairs (pre-tanh'd)
    const u16*  __restrict__ maskT, // [144][NPIX] fp16 (pre-sigmoid'd)
    const u16*  __restrict__ wdf,   // [36][4][64][8] fp16 fragment-major
    const float* __restrict__ bdcn,
    float* __restrict__ part)       // [3][N*64*HW] fp32 partials
{
    const int t    = threadIdx.x;
    const int xb   = blockIdx.x;                    // 0..575
    const int xw   = (xb & 7) * 72 + (xb >> 3);     // XCD-contiguous tile id
    const int p0   = xw * 64;
    const int ks   = blockIdx.y;                    // K-split index 0..2
    const int ln   = t & 63;
    const int wv   = t >> 6;
    const int l15  = ln & 15;
    const int lg   = ln >> 4;
    const int n    = p0 / HW;
    const int rem0 = p0 - n * HW;
    const int p    = p0 + wv * 16 + l15;    // this thread's sampling pixel
    const int rem  = rem0 + wv * 16 + l15;
    const int h    = rem / WW;
    const int w    = rem - h * WW;

    const char* pTc = (const char*)pairT;
    const char* mTc = (const char*)maskT;
    const char* xTc = (const char*)xT;
    const u32 p4   = (u32)p << 2;
    const u32 p2   = (u32)p << 1;
    const u32 nb16 = (u32)(n * HW) << 4;            // xT image base, 16B/pixel

    // flows + grid bases hoisted (f?yh = flow_y + h, f?xw = flow_x + w)
    const float f1yh = f1[(size_t)(n * 2 + 1) * HW + rem] + (float)h;
    const float f1xw = f1[(size_t)(n * 2 + 0) * HW + rem] + (float)w;
    const float f2yh = f2[(size_t)(n * 2 + 1) * HW + rem] + (float)h;
    const float f2xw = f2[(size_t)(n * 2 + 0) * HW + rem] + (float)w;

    // nt loads: read-once streams must not evict the hot xT window from L2
    auto scal = [&](int sl, u32& yx, u32& mr) {
        yx = __builtin_nontemporal_load(
                 (const u32*)(pTc + ((u32)sl * (u32)(NPIX * 4) + p4)));
        mr = (u32)__builtin_nontemporal_load(
                 (const u16*)(mTc + ((u32)sl * (u32)(NPIX * 2) + p2)));
    };

    // coords: bilinear weights (mask folded, packed fp16) + 4 gathers
    auto coords = [&](int sl, u32 yx, u32 mr,
                      uint4& q00, uint4& q01, uint4& q10, uint4& q11,
                      u32& W00, u32& W01, u32& W10, u32& W11) {
        const int g  = (sl * 57) >> 9;            // sl/9 exact for sl<144
        const int kt = sl - 9 * g;
        const int ky = (kt * 11) >> 5;            // kt/3 for kt<9
        const int kx = kt - 3 * ky;
        const float fy = (g < 8) ? f1yh : f2yh;
        const float fx = (g < 8) ? f1xw : f2xw;
        const float py  = f16lo(yx) + (fy + (float)(ky - 1));
        const float pxx = f16hi(yx) + (fx + (float)(kx - 1));
        const float m   = f16lo(mr);

        const float y0f = floorf(py), x0f = floorf(pxx);
        const int   iy0 = (int)y0f,   ix0 = (int)x0f;
        const float wy = py - y0f, wx = pxx - x0f;
        const bool v0y = ((unsigned)iy0 < HH);
        const bool v1y = ((unsigned)(iy0 + 1) < HH);
        const bool v0x = ((unsigned)ix0 < WW);
        const bool v1x = ((unsigned)(ix0 + 1) < WW);
        const float wy0m = (1.0f - wy) * m, wy1m = wy * m;
        const float w00 = (v0y && v0x) ? wy0m * (1.0f - wx) : 0.0f;
        const float w01 = (v0y && v1x) ? wy0m * wx          : 0.0f;
        const float w10 = (v1y && v0x) ? wy1m * (1.0f - wx) : 0.0f;
        const float w11 = (v1y && v1x) ? wy1m * wx          : 0.0f;
        W00 = pkrtz(w00, w00);  W01 = pkrtz(w01, w01);
        W10 = pkrtz(w10, w10);  W11 = pkrtz(w11, w11);

        const int iy0c = min(max(iy0, 0), HH - 1);
        const int iy1c = min(max(iy0 + 1, 0), HH - 1);
        const int ix0c = min(max(ix0, 0), WW - 1);
        const int ix1c = min(max(ix0 + 1, 0), WW - 1);
        const u32 gof = (u32)g * (u32)(NPIX * 16) + nb16;
        const u32 r0  = gof + (u32)iy0c * (u32)(WW * 16);
        const u32 r1  = gof + (u32)iy1c * (u32)(WW * 16);
        const u32 c0  = (u32)ix0c << 4;
        const u32 c1  = (u32)ix1c << 4;
        q00 = *(const uint4*)(xTc + (r0 + c0));
        q01 = *(const uint4*)(xTc + (r0 + c1));
        q10 = *(const uint4*)(xTc + (r1 + c0));
        q11 = *(const uint4*)(xTc + (r1 + c1));
    };

    // packed fp16 bilinear blend: 4 words x (1 pk_mul + 3 pk_fma)
    auto blend = [&](const uint4& q00, const uint4& q01,
                     const uint4& q10, const uint4& q11,
                     u32 W00, u32 W01, u32 W10, u32 W11) -> uint4 {
        const f16x2 A = u2h(W00), B = u2h(W01), C = u2h(W10), D = u2h(W11);
        auto bl1 = [&](u32 a, u32 b, u32 c, u32 d) -> u32 {
            f16x2 r = u2h(a) * A;
            r = __builtin_elementwise_fma(u2h(b), B, r);
            r = __builtin_elementwise_fma(u2h(c), C, r);
            r = __builtin_elementwise_fma(u2h(d), D, r);
            return h2u(r);
        };
        return make_uint4(bl1(q00.x, q01.x, q10.x, q11.x),
                          bl1(q00.y, q01.y, q10.y, q11.y),
                          bl1(q00.z, q01.z, q10.z, q11.z),
                          bl1(q00.w, q01.w, q10.w, q11.w));
    };

    v4f acc[4];
    #pragma unroll
    for (int i = 0; i < 4; ++i) acc[i] = (v4f){0.f, 0.f, 0.f, 0.f};

    const int cc0 = ks * 12;
    const int sb  = cc0 * 4 + lg;           // slot of sample i = sb + 4*i
    const char* wb = (const char*)wdf + ((u32)cc0 << 12) + ((u32)ln << 4);

    // ---- pipeline state (named, no runtime-indexed arrays) ----
    uint4 qA00, qA01, qA10, qA11;  u32 WA00, WA01, WA10, WA11;
    uint4 qB00, qB01, qB10, qB11;  u32 WB00, WB01, WB10, WB11;
    u32 yxN, mrN;

    {   // prologue: fill A (sample 0), B (sample 1); preload scalars for 2
        u32 yx, mr;
        scal(sb, yx, mr);
        coords(sb, yx, mr, qA00, qA01, qA10, qA11, WA00, WA01, WA10, WA11);
        scal(sb + 4, yx, mr);
        coords(sb + 4, yx, mr, qB00, qB01, qB10, qB11, WB00, WB01, WB10, WB11);
        scal(sb + 8, yxN, mrN);
    }

    #pragma unroll 1
    for (int j = 0; j < 12; j += 2) {
        {   // EVEN: consume A (sample j); refill A with sample j+2
            const char* wj = wb + ((u32)j << 12);
            f16x8 aW0 = q2h8(*(const uint4*)(wj));
            f16x8 aW1 = q2h8(*(const uint4*)(wj + 1024));
            f16x8 aW2 = q2h8(*(const uint4*)(wj + 2048));
            f16x8 aW3 = q2h8(*(const uint4*)(wj + 3072));
            f16x8 bP = q2h8(blend(qA00, qA01, qA10, qA11, WA00, WA01, WA10, WA11));
            acc[0] = __builtin_amdgcn_mfma_f32_16x16x32_f16(bP, aW0, acc[0], 0, 0, 0);
            acc[1] = __builtin_amdgcn_mfma_f32_16x16x32_f16(bP, aW1, acc[1], 0, 0, 0);
            acc[2] = __builtin_amdgcn_mfma_f32_16x16x32_f16(bP, aW2, acc[2], 0, 0, 0);
            acc[3] = __builtin_amdgcn_mfma_f32_16x16x32_f16(bP, aW3, acc[3], 0, 0, 0);
            if (j + 2 < 12)
                coords(sb + (j + 2) * 4, yxN, mrN,
                       qA00, qA01, qA10, qA11, WA00, WA01, WA10, WA11);
            if (j + 3 < 12) scal(sb + (j + 3) * 4, yxN, mrN);
        }
        {   // ODD: consume B (sample j+1); refill B with sample j+3
            const char* wj = wb + ((u32)(j + 1) << 12);
            f16x8 aW0 = q2h8(*(const uint4*)(wj));
            f16x8 aW1 = q2h8(*(const uint4*)(wj + 1024));
            f16x8 aW2 = q2h8(*(const uint4*)(wj + 2048));
            f16x8 aW3 = q2h8(*(const uint4*)(wj + 3072));
            f16x8 bP = q2h8(blend(qB00, qB01, qB10, qB11, WB00, WB01, WB10, WB11));
            acc[0] = __builtin_amdgcn_mfma_f32_16x16x32_f16(bP, aW0, acc[0], 0, 0, 0);
            acc[1] = __builtin_amdgcn_mfma_f32_16x16x32_f16(bP, aW1, acc[1], 0, 0, 0);
            acc[2] = __builtin_amdgcn_mfma_f32_16x16x32_f16(bP, aW2, acc[2], 0, 0, 0);
            acc[3] = __builtin_amdgcn_mfma_f32_16x16x32_f16(bP, aW3, acc[3], 0, 0, 0);
            if (j + 3 < 12)
                coords(sb + (j + 3) * 4, yxN, mrN,
                       qB00, qB01, qB10, qB11, WB00, WB01, WB10, WB11);
            if (j + 4 < 12) scal(sb + (j + 4) * 4, yxN, mrN);
        }
    }

    float* yp = part + (size_t)ks * ((size_t)NPIX * C_OUT);
    #pragma unroll
    for (int m = 0; m < 4; ++m) {
        const int o = m * 16 + l15;
        const float bd = (ks == 0) ? bdcn[o] : 0.0f;   // bias once, in split 0
        const size_t idx = (size_t)(n * C_OUT + o) * HW + rem0 + wv * 16 + lg * 4;
        v4f out = {acc[m][0] + bd, acc[m][1] + bd, acc[m][2] + bd, acc[m][3] + bd};
        __builtin_nontemporal_store(out, (v4f*)&yp[idx]);   // write-once stream
    }
}

// ---------------------------------------------------------------------------
// Sum the 3 fp32 partials -> y. Pure BW, float4.
// ---------------------------------------------------------------------------
__global__ __launch_bounds__(256) void dcn_reduce(
    const float* __restrict__ part, float* __restrict__ y)
{
    const size_t i = ((size_t)blockIdx.x * 256 + threadIdx.x) * 4;
    const size_t S = (size_t)NPIX * C_OUT;
    float4 a = *(const float4*)&part[i];
    float4 b = *(const float4*)&part[i + S];
    float4 c = *(const float4*)&part[i + 2 * S];
    *(float4*)&y[i] = make_float4(a.x + b.x + c.x, a.y + b.y + c.y,
                                  a.z + b.z + c.z, a.w + b.w + c.w);
}

// ---------------------------------------------------------------------------
extern "C" void kernel_launch(void* const* d_in, const int* in_sizes, int n_in,
                              void* d_out, int out_size, void* d_ws, size_t ws_size,
                              hipStream_t stream) {
    const float* x  = (const float*)d_in[0];
    const float* ef = (const float*)d_in[1];
    const float* f1 = (const float*)d_in[2];
    const float* f2 = (const float*)d_in[3];
    const float* w0 = (const float*)d_in[4];
    const float* b0 = (const float*)d_in[5];
    const float* w1 = (const float*)d_in[6];
    const float* b1 = (const float*)d_in[7];
    const float* w2 = (const float*)d_in[8];
    const float* b2 = (const float*)d_in[9];
    const float* w3 = (const float*)d_in[10];
    const float* b3 = (const float*)d_in[11];
    const float* wd = (const float*)d_in[12];
    const float* bd = (const float*)d_in[13];
    float* y = (float*)d_out;
    char* wsb = (char*)d_ws;

    // Workspace (bytes), 16B-aligned; total ~75.4 MB.
    // part (28.3 MB fp32) aliases catT+h0T+h1T, all dead by dcn time.
    u16* catT  = (u16*)(wsb + 0);          // 18,874,368
    u16* h0T   = (u16*)(wsb + 18874368);   //  4,718,592
    u16* h1T   = (u16*)(wsb + 23592960);   //  4,718,592
    u16* h2T   = (u16*)(wsb + 28311552);   //  4,718,592
    u32* pairT = (u32*)(wsb + 33030144);   // 21,233,664
    u16* maskT = (u16*)(wsb + 54263808);   // 10,616,832
    u16* w0p   = (u16*)(wsb + 64880640);   //    294,912
    u16* w1p   = (u16*)(wsb + 65175552);   //     73,728
    u16* w2p   = (u16*)(wsb + 65249280);   //     73,728
    u16* w3p   = (u16*)(wsb + 65323008);   //    516,096
    u16* wdf   = (u16*)(wsb + 65839104);   //    147,456
    u16* xT    = (u16*)(wsb + 65986560);   //  9,437,184 -> ends 75,423,744
    float* part = (float*)(wsb + 0);       // 28,311,552 (alias, 3 partials)

    prep_catT<<<dim3(NPIX / 64, 4), 256, 0, stream>>>(ef, f1, f2, catT);
    prep_xT  <<<dim3(NPIX / 64, 2), 256, 0, stream>>>(x, xT);
    pack_all <<<dim3(552960 / 256), 256, 0, stream>>>(
        w0, w0p, w1, w1p, w2, w2p, w3, w3p, wd, wdf);

    conv_mfma<256, 4, 64, true,  false, 1><<<dim3(768), 256, 0, stream>>>(
        catT, w0p, b0, 64, h0T, nullptr, nullptr);
    conv_mfma< 64, 1, 64, true,  false, 1><<<dim3(768), 256, 0, stream>>>(
        h0T, w1p, b1, 64, h1T, nullptr, nullptr);
    conv_mfma< 64, 1, 64, true,  false, 1><<<dim3(768), 256, 0, stream>>>(
        h1T, w2p, b2, 64, h2T, nullptr, nullptr);
    conv_mfma< 64, 1, 448, false, true, 7><<<dim3(NB * HH, 2), 256, 0, stream>>>(
        h2T, w3p, b3, 432, nullptr, pairT, maskT);

    dcn_fused<<<dim3(NPIX / 64, 3), 256, 0, stream>>>(
        xT, f1, f2, pairT, maskT, wdf, bd, part);
    dcn_reduce<<<dim3(NPIX * C_OUT / 4 / 256), 256, 0, stream>>>(part, y);
}

// Round 10
// 134.876 us; speedup vs baseline: 1.0935x; 1.0935x over previous
//
#include <hip/hip_runtime.h>
#include <math.h>

#define NB 4
#define HH 96
#define WW 96
#define HW (HH*WW)
#define NPIX (NB*HW)
#define C_IN 128
#define C_OUT 64
#define DGRP 16
#define CG 8

typedef short v8s __attribute__((ext_vector_type(8)));
typedef float v4f __attribute__((ext_vector_type(4)));
typedef unsigned short u16;
typedef unsigned int u32;

__device__ __forceinline__ u16 f2bf(float x) {
    u32 u = __float_as_uint(x);
    u32 r = (u + 0x7FFFu + ((u >> 16) & 1u)) >> 16;   // RNE
    return (u16)r;
}
__device__ __forceinline__ float bf2f(u16 h) {
    return __uint_as_float(((u32)h) << 16);
}
__device__ __forceinline__ float lo_bf(u32 w) { return __uint_as_float(w << 16); }
__device__ __forceinline__ float hi_bf(u32 w) { return __uint_as_float(w & 0xFFFF0000u); }
__device__ __forceinline__ float ftanh(float x) {
    float e = __expf(2.0f * x);
    return 1.0f - 2.0f / (e + 1.0f);
}
__device__ __forceinline__ float fsigm(float x) {
    return 1.0f / (1.0f + __expf(-x));
}
__device__ __forceinline__ v8s u4_to_v8s(uint4 q) {
    union { uint4 q; v8s s; } u; u.q = q; return u.s;
}
// HW packed fp32->bf16 RNE: dst.lo16 = bf16(a), dst.hi16 = bf16(b).
__device__ __forceinline__ u32 cvtpk(float a, float b) {
    u32 r;
    asm("v_cvt_pk_bf16_f32 %0, %1, %2" : "=v"(r) : "v"(a), "v"(b));
    return r;
}

// ---------------------------------------------------------------------------
// Prep 1: concat(extra_feat, flow1, flow2) -> pixel-major bf16 [NPIX][256]
// ---------------------------------------------------------------------------
__global__ __launch_bounds__(256) void prep_catT(
    const float* __restrict__ ef, const float* __restrict__ f1,
    const float* __restrict__ f2, u16* __restrict__ catT)
{
    __shared__ float T[64][65];
    const int t   = threadIdx.x;
    const int p   = blockIdx.x * 64;
    const int ch0 = blockIdx.y * 64;
    const int n   = p / HW;
    const int rem = p - n * HW;
    const int px  = t & 63;
    const int wv  = t >> 6;
    #pragma unroll
    for (int kk = 0; kk < 16; ++kk) {
        int chl = wv * 16 + kk;
        int ch  = ch0 + chl;
        float v = 0.f;
        if (ch < 192)      v = ef[(size_t)(n * 192 + ch) * HW + rem + px];
        else if (ch < 194) v = f1[(size_t)(n * 2 + (ch - 192)) * HW + rem + px];
        else if (ch < 196) v = f2[(size_t)(n * 2 + (ch - 194)) * HW + rem + px];
        T[chl][px] = v;
    }
    __syncthreads();
    const int s = t & 7;
    #pragma unroll
    for (int it = 0; it < 2; ++it) {
        int pxo = (t >> 3) + it * 32;
        u32 w0 = (u32)f2bf(T[s*8+0][pxo]) | ((u32)f2bf(T[s*8+1][pxo]) << 16);
        u32 w1 = (u32)f2bf(T[s*8+2][pxo]) | ((u32)f2bf(T[s*8+3][pxo]) << 16);
        u32 w2 = (u32)f2bf(T[s*8+4][pxo]) | ((u32)f2bf(T[s*8+5][pxo]) << 16);
        u32 w3 = (u32)f2bf(T[s*8+6][pxo]) | ((u32)f2bf(T[s*8+7][pxo]) << 16);
        *(uint4*)&catT[((size_t)(p + pxo)) * 256 + ch0 + s * 8] = make_uint4(w0, w1, w2, w3);
    }
}

// ---------------------------------------------------------------------------
// Prep: x [N,128,H,W] fp32 -> xT group-major bf16 [16 groups][NPIX][8]
// ---------------------------------------------------------------------------
__global__ __launch_bounds__(256) void prep_xT(
    const float* __restrict__ x, u16* __restrict__ xT)
{
    __shared__ float T[64][65];
    const int t   = threadIdx.x;
    const int p   = blockIdx.x * 64;
    const int ch0 = blockIdx.y * 64;
    const int n   = p / HW;
    const int rem = p - n * HW;
    const int px  = t & 63;
    const int wv  = t >> 6;
    #pragma unroll
    for (int kk = 0; kk < 16; ++kk) {
        int chl = wv * 16 + kk;
        T[chl][px] = x[(size_t)(n * C_IN + ch0 + chl) * HW + rem + px];
    }
    __syncthreads();
    const int s = t & 7;
    #pragma unroll
    for (int it = 0; it < 2; ++it) {
        int pxo = (t >> 3) + it * 32;
        u32 w0 = (u32)f2bf(T[s*8+0][pxo]) | ((u32)f2bf(T[s*8+1][pxo]) << 16);
        u32 w1 = (u32)f2bf(T[s*8+2][pxo]) | ((u32)f2bf(T[s*8+3][pxo]) << 16);
        u32 w2 = (u32)f2bf(T[s*8+4][pxo]) | ((u32)f2bf(T[s*8+5][pxo]) << 16);
        u32 w3 = (u32)f2bf(T[s*8+6][pxo]) | ((u32)f2bf(T[s*8+7][pxo]) << 16);
        *(uint4*)&xT[((size_t)(ch0 / 8 + s) * NPIX + (p + pxo)) * 8] = make_uint4(w0, w1, w2, w3);
    }
}

// ---------------------------------------------------------------------------
// ONE fused weight-pack kernel.
// ---------------------------------------------------------------------------
__device__ __forceinline__ void pack_wf_one(
    const float* __restrict__ w, u16* __restrict__ wp,
    int Cout, int CoutPad, int CIN, int CIP, int idx)
{
    const int NKF = CIP / 32, NOG = CoutPad / 16;
    int c    = idx & 7;
    int ln   = (idx >> 3) & 63;
    int rest = idx >> 9;
    int og   = rest % NOG; rest /= NOG;
    int kfg  = rest % NKF;
    int tap  = rest / NKF;
    int l15 = ln & 15, lg = ln >> 4;
    int o  = og * 16 + l15;
    int ci = kfg * 32 + lg * 8 + c;
    float v = (o < Cout && ci < CIN) ? w[((size_t)o * CIN + ci) * 9 + tap] : 0.f;
    wp[idx] = f2bf(v);
}

__global__ __launch_bounds__(256) void pack_all(
    const float* __restrict__ w0, u16* __restrict__ w0p,
    const float* __restrict__ w1, u16* __restrict__ w1p,
    const float* __restrict__ w2, u16* __restrict__ w2p,
    const float* __restrict__ w3, u16* __restrict__ w3p,
    const float* __restrict__ wd, u16* __restrict__ wdf)
{
    int idx = blockIdx.x * 256 + threadIdx.x;
    if (idx < 147456) { pack_wf_one(w0, w0p, 64, 64, 196, 256, idx); return; }
    idx -= 147456;
    if (idx < 36864)  { pack_wf_one(w1, w1p, 64, 64, 64, 64, idx); return; }
    idx -= 36864;
    if (idx < 36864)  { pack_wf_one(w2, w2p, 64, 64, 64, 64, idx); return; }
    idx -= 36864;
    if (idx < 258048) { pack_wf_one(w3, w3p, 432, 448, 64, 64, idx); return; }
    idx -= 258048;
    {   // pack_wdf
        int c  = idx & 7;
        int ln = (idx >> 3) & 63;
        int m  = (idx >> 9) & 3;
        int kk = idx >> 11;
        int l15 = ln & 15, lg = ln >> 4;
        int o = m * 16 + l15;
        int slot = kk * 4 + lg;
        int g = slot / 9, kt = slot - 9 * g;
        wdf[idx] = f2bf(wd[((size_t)(o * C_IN + g * CG + c)) * 9 + kt]);
    }
}

// ---------------------------------------------------------------------------
// MFMA implicit-GEMM 3x3 conv, 256 thr = 4 waves. Fragment-major weights.
// (R6 configuration: conv3 writes RAW bf16 pairs/mask; tanh/sigmoid live in
// dcn_fused -- R7's epilogue move cost more in conv3 than it saved in dcn.)
// ---------------------------------------------------------------------------
template<int CIP, int NCHUNK, int OST, bool LRELU, bool TOUT, int NOB>
__global__ __launch_bounds__(256) void conv_mfma(
    const u16* __restrict__ inT,
    const u16* __restrict__ wp,
    const float* __restrict__ bias,
    int CoutReal,
    u16* __restrict__ outT,
    u32* __restrict__ pairT,
    u16* __restrict__ maskT)
{
    constexpr int COLS  = (NOB > 1) ? 100 : 50;        // padded row stride
    constexpr int LTILE = 3 * COLS * 64;
    constexpr int LSZ   = (NCHUNK > 1) ? 2 * LTILE : LTILE;
    constexpr int NKF   = CIP / 32;
    constexpr int NOG   = OST / 16;
    __shared__ __align__(16) u16 L[LSZ];

    const int t   = threadIdx.x;
    const int tb  = blockIdx.x;
    const int row = (NOB > 1) ? tb : (tb >> 1);
    const int p0  = (NOB > 1) ? 0 : (tb & 1) * 48;
    const int n   = row / HH;
    const int h   = row - n * HH;
    const int ln  = t & 63;
    const int wv  = t >> 6;          // 0..3
    const int l15 = ln & 15;
    const int lg  = ln >> 4;

    auto stage = [&](int ch, int buf) {
        const int cb = ch * 64;
        const int NCOL = (NOB > 1) ? 98 : 50;
        const int NTASK = 3 * NCOL * 8;
        u16* Lb = &L[buf * LTILE];
        #pragma unroll
        for (int it = 0; it < (NTASK + 255) / 256; ++it) {
            int task = it * 256 + t;
            if (task < NTASK) {
                int s  = task & 7;
                int cl = task >> 3;
                int r3 = cl / NCOL;
                int c  = cl - r3 * NCOL;
                int yy = h + r3 - 1;
                int xx = p0 + c - 1;
                uint4 v = make_uint4(0u, 0u, 0u, 0u);
                if ((unsigned)yy < HH && (unsigned)xx < WW)
                    v = *(const uint4*)&inT[((size_t)(n * HW + yy * WW + xx)) * CIP + cb + s * 8];
                *(uint4*)&Lb[(r3 * COLS + c) * 64 + ((s ^ (c & 7)) * 8)] = v;
            }
        }
    };

    if constexpr (NOB == 1) {
        v4f acc[3];
        #pragma unroll
        for (int i = 0; i < 3; ++i) acc[i] = (v4f){0.f, 0.f, 0.f, 0.f};

        stage(0, 0);
        for (int ch = 0; ch < NCHUNK; ++ch) {
            __syncthreads();
            if (ch + 1 < NCHUNK) stage(ch + 1, (ch + 1) & 1);
            const u16* Lb = &L[(ch & 1) * LTILE];
            #pragma unroll
            for (int tap = 0; tap < 9; ++tap) {
                const int ty = tap / 3, tx = tap - ty * 3;
                #pragma unroll
                for (int kf = 0; kf < 2; ++kf) {
                    v8s b = *(const v8s*)&wp[((((size_t)tap * NKF + (ch * 2 + kf)) * NOG + wv) * 64 + ln) * 8];
                    #pragma unroll
                    for (int fm = 0; fm < 3; ++fm) {
                        int c = fm * 16 + l15 + tx;
                        v8s a = *(const v8s*)&Lb[(ty * COLS + c) * 64 + (((kf * 4 + lg) ^ (c & 7)) * 8)];
                        acc[fm] = __builtin_amdgcn_mfma_f32_16x16x32_bf16(a, b, acc[fm], 0, 0, 0);
                    }
                }
            }
        }

        int o = wv * 16 + l15;
        float bv = (o < CoutReal) ? bias[o] : 0.f;
        #pragma unroll
        for (int fm = 0; fm < 3; ++fm) {
            #pragma unroll
            for (int r = 0; r < 4; ++r) {
                int px = p0 + fm * 16 + lg * 4 + r;
                float v = acc[fm][r] + bv;
                if (LRELU) v = (v >= 0.f) ? v : 0.1f * v;
                outT[((size_t)(n * HW + h * WW + px)) * OST + o] = f2bf(v);
            }
        }
    } else {
        stage(0, 0);
        __syncthreads();
        const size_t gpix = (size_t)n * HW + h * WW;
        const int ob_lo = blockIdx.y * 4;
        const int ob_hi = (ob_lo + 4 < NOB) ? ob_lo + 4 : NOB;

        for (int ob = ob_lo; ob < ob_hi; ++ob) {
            const int obase = ob * 64 + wv * 16;
            if (obase >= 432) continue;

            v4f acc[6];
            #pragma unroll
            for (int i = 0; i < 6; ++i) acc[i] = (v4f){0.f, 0.f, 0.f, 0.f};

            #pragma unroll
            for (int tap = 0; tap < 9; ++tap) {
                const int ty = tap / 3, tx = tap - ty * 3;
                #pragma unroll
                for (int kf = 0; kf < 2; ++kf) {
                    v8s bw = *(const v8s*)&wp[((((size_t)tap * NKF + kf) * NOG + (ob * 4 + wv)) * 64 + ln) * 8];
                    #pragma unroll
                    for (int fm = 0; fm < 6; ++fm) {
                        int c = fm * 16 + l15 + tx;
                        v8s a = *(const v8s*)&L[(ty * COLS + c) * 64 + (((kf * 4 + lg) ^ (c & 7)) * 8)];
                        acc[fm] = __builtin_amdgcn_mfma_f32_16x16x32_bf16(bw, a, acc[fm], 0, 0, 0);
                    }
                }
            }

            float bv[4];
            #pragma unroll
            for (int r = 0; r < 4; ++r) bv[r] = bias[obase + lg * 4 + r];

            if (obase < 288) {
                const int pr = (obase + lg * 4) >> 1;
                #pragma unroll
                for (int fm = 0; fm < 6; ++fm) {
                    const size_t pix = gpix + fm * 16 + l15;
                    u32 v0 = (u32)f2bf(acc[fm][0] + bv[0]) | ((u32)f2bf(acc[fm][1] + bv[1]) << 16);
                    u32 v1 = (u32)f2bf(acc[fm][2] + bv[2]) | ((u32)f2bf(acc[fm][3] + bv[3]) << 16);
                    pairT[(size_t)pr * NPIX + pix]       = v0;
                    pairT[(size_t)(pr + 1) * NPIX + pix] = v1;
                }
            } else {
                #pragma unroll
                for (int fm = 0; fm < 6; ++fm) {
                    const size_t pix = gpix + fm * 16 + l15;
                    #pragma unroll
                    for (int r = 0; r < 4; ++r) {
                        int mch = obase + lg * 4 + r - 288;
                        maskT[(size_t)mch * NPIX + pix] = f2bf(acc[fm][r] + bv[r]);
                    }
                }
            }
        }
    }
}

// ---------------------------------------------------------------------------
// Fused DCN sample+GEMM. R10: IN-BLOCK K-split.
// Block = 32 pixels x 3 K-splits = 6 waves (384 thr). Each 2-wave set runs
// its 12 chunks exactly as the R6 body (same 6912 total waves, same per-wave
// work, XCD swizzle preserved: 1152 = 8 x 144). Sets 1,2 dump acc to LDS
// (16KB, stride-16B b128 conflict-free); set 0 sums + bias + writes y ONCE.
// Kills the part buffer (28MB w + 57MB r) and the dcn_reduce dispatch:
// ~85MB HBM round-trip (~12us) for ~1us of LDS traffic.
// (R9 post-mortem: nt stores/loads + fp16 blend regressed dur 46->54,
// WRITE 28->37MB -- nt fp32 stores flush partial lines. Fully reverted.)
// ---------------------------------------------------------------------------
__global__ __launch_bounds__(384) void dcn_fused(
    const u16* __restrict__ xT,     // [16][NPIX][8] bf16
    const float* __restrict__ f1,
    const float* __restrict__ f2,
    const u32*  __restrict__ pairT, // [144][NPIX] raw bf16 offset pairs
    const u16*  __restrict__ maskT, // [144][NPIX] raw bf16 mask
    const u16*  __restrict__ wdf,   // [36][4][64][8] bf16 fragment-major
    const float* __restrict__ bdcn,
    float* __restrict__ y)          // [N,64,H,W] fp32
{
    __shared__ __align__(16) v4f R[2][4][128];   // 16KB: sets 1,2 partials

    const int t    = threadIdx.x;                  // 0..383
    const int xb   = blockIdx.x;                   // 0..1151
    const int xw   = (xb & 7) * 144 + (xb >> 3);   // XCD-contiguous tile id
    const int p0   = xw * 32;
    const int w6   = t >> 6;                       // wave 0..5
    const int ks   = w6 >> 1;                      // K-split set 0..2
    const int wvs  = w6 & 1;                       // wave within set 0..1
    const int ln   = t & 63;
    const int l15  = ln & 15;
    const int lg   = ln >> 4;
    const int ts   = wvs * 64 + ln;                // 0..127, id within set
    const int n    = p0 / HW;
    const int rem0 = p0 - n * HW;
    const int p    = p0 + wvs * 16 + l15;   // this thread's sampling pixel
    const int rem  = rem0 + wvs * 16 + l15;
    const int h    = rem / WW;
    const int w    = rem - h * WW;

    const char* pTc = (const char*)pairT;
    const char* mTc = (const char*)maskT;
    const char* xTc = (const char*)xT;
    const u32 p4   = (u32)p << 2;
    const u32 p2   = (u32)p << 1;
    const u32 nb16 = (u32)(n * HW) << 4;           // xT image base, 16B/pixel

    // flows + grid bases hoisted (f?yh = flow_y + h, f?xw = flow_x + w)
    const float f1yh = f1[(size_t)(n * 2 + 1) * HW + rem] + (float)h;
    const float f1xw = f1[(size_t)(n * 2 + 0) * HW + rem] + (float)w;
    const float f2yh = f2[(size_t)(n * 2 + 1) * HW + rem] + (float)h;
    const float f2xw = f2[(size_t)(n * 2 + 0) * HW + rem] + (float)w;

    auto scal = [&](int sl, u32& yx, float& mr) {
        yx = *(const u32*)(pTc + ((u32)sl * (u32)(NPIX * 4) + p4));
        mr = bf2f(*(const u16*)(mTc + ((u32)sl * (u32)(NPIX * 2) + p2)));
    };

    // coords: bilinear weights (mask folded) + issue 4 gathers
    auto coords = [&](int sl, u32 yx, float mr,
                      uint4& q00, uint4& q01, uint4& q10, uint4& q11,
                      float& w00, float& w01, float& w10, float& w11) {
        const int g  = (sl * 57) >> 9;            // sl/9 exact for sl<144
        const int kt = sl - 9 * g;
        const int ky = (kt * 11) >> 5;            // kt/3 for kt<9
        const int kx = kt - 3 * ky;
        const float fy = (g < 8) ? f1yh : f2yh;
        const float fx = (g < 8) ? f1xw : f2xw;
        const float py  = 10.0f * ftanh(lo_bf(yx)) + (fy + (float)(ky - 1));
        const float pxx = 10.0f * ftanh(hi_bf(yx)) + (fx + (float)(kx - 1));
        const float m   = fsigm(mr);

        const float y0f = floorf(py), x0f = floorf(pxx);
        const int   iy0 = (int)y0f,   ix0 = (int)x0f;
        const float wy = py - y0f, wx = pxx - x0f;
        const bool v0y = ((unsigned)iy0 < HH);
        const bool v1y = ((unsigned)(iy0 + 1) < HH);
        const bool v0x = ((unsigned)ix0 < WW);
        const bool v1x = ((unsigned)(ix0 + 1) < WW);
        const float wy0m = (1.0f - wy) * m, wy1m = wy * m;
        w00 = (v0y && v0x) ? wy0m * (1.0f - wx) : 0.0f;
        w01 = (v0y && v1x) ? wy0m * wx          : 0.0f;
        w10 = (v1y && v0x) ? wy1m * (1.0f - wx) : 0.0f;
        w11 = (v1y && v1x) ? wy1m * wx          : 0.0f;

        const int iy0c = min(max(iy0, 0), HH - 1);
        const int iy1c = min(max(iy0 + 1, 0), HH - 1);
        const int ix0c = min(max(ix0, 0), WW - 1);
        const int ix1c = min(max(ix0 + 1, 0), WW - 1);
        const u32 gof = (u32)g * (u32)(NPIX * 16) + nb16;
        const u32 r0  = gof + (u32)iy0c * (u32)(WW * 16);
        const u32 r1  = gof + (u32)iy1c * (u32)(WW * 16);
        const u32 c0  = (u32)ix0c << 4;
        const u32 c1  = (u32)ix1c << 4;
        q00 = *(const uint4*)(xTc + (r0 + c0));
        q01 = *(const uint4*)(xTc + (r0 + c1));
        q10 = *(const uint4*)(xTc + (r1 + c0));
        q11 = *(const uint4*)(xTc + (r1 + c1));
    };

    auto blend = [&](const uint4& q00, const uint4& q01,
                     const uint4& q10, const uint4& q11,
                     float w00, float w01, float w10, float w11) -> v8s {
        u32 pv0 = cvtpk(
            w00*lo_bf(q00.x) + w01*lo_bf(q01.x) + w10*lo_bf(q10.x) + w11*lo_bf(q11.x),
            w00*hi_bf(q00.x) + w01*hi_bf(q01.x) + w10*hi_bf(q10.x) + w11*hi_bf(q11.x));
        u32 pv1 = cvtpk(
            w00*lo_bf(q00.y) + w01*lo_bf(q01.y) + w10*lo_bf(q10.y) + w11*lo_bf(q11.y),
            w00*hi_bf(q00.y) + w01*hi_bf(q01.y) + w10*hi_bf(q10.y) + w11*hi_bf(q11.y));
        u32 pv2 = cvtpk(
            w00*lo_bf(q00.z) + w01*lo_bf(q01.z) + w10*lo_bf(q10.z) + w11*lo_bf(q11.z),
            w00*hi_bf(q00.z) + w01*hi_bf(q01.z) + w10*hi_bf(q10.z) + w11*hi_bf(q11.z));
        u32 pv3 = cvtpk(
            w00*lo_bf(q00.w) + w01*lo_bf(q01.w) + w10*lo_bf(q10.w) + w11*lo_bf(q11.w),
            w00*hi_bf(q00.w) + w01*hi_bf(q01.w) + w10*hi_bf(q10.w) + w11*hi_bf(q11.w));
        return u4_to_v8s(make_uint4(pv0, pv1, pv2, pv3));
    };

    v4f acc[4];
    #pragma unroll
    for (int i = 0; i < 4; ++i) acc[i] = (v4f){0.f, 0.f, 0.f, 0.f};

    const int cc0 = ks * 12;
    const int sb  = cc0 * 4 + lg;           // slot of sample i = sb + 4*i
    const char* wb = (const char*)wdf + ((u32)cc0 << 12) + ((u32)ln << 4);

    // ---- pipeline state (named, no runtime-indexed arrays) ----
    uint4 qA00, qA01, qA10, qA11;  float wA00, wA01, wA10, wA11;
    uint4 qB00, qB01, qB10, qB11;  float wB00, wB01, wB10, wB11;
    u32 yxN; float mrN;

    {   // prologue: fill A (sample 0), B (sample 1); preload scalars for 2
        u32 yx; float mr;
        scal(sb, yx, mr);
        coords(sb, yx, mr, qA00, qA01, qA10, qA11, wA00, wA01, wA10, wA11);
        scal(sb + 4, yx, mr);
        coords(sb + 4, yx, mr, qB00, qB01, qB10, qB11, wB00, wB01, wB10, wB11);
        scal(sb + 8, yxN, mrN);
    }

    #pragma unroll 1
    for (int j = 0; j < 12; j += 2) {
        {   // EVEN: consume A (sample j); refill A with sample j+2
            const char* wj = wb + ((u32)j << 12);
            v8s aW0 = *(const v8s*)(wj);
            v8s aW1 = *(const v8s*)(wj + 1024);
            v8s aW2 = *(const v8s*)(wj + 2048);
            v8s aW3 = *(const v8s*)(wj + 3072);
            v8s bP = blend(qA00, qA01, qA10, qA11, wA00, wA01, wA10, wA11);
            acc[0] = __builtin_amdgcn_mfma_f32_16x16x32_bf16(bP, aW0, acc[0], 0, 0, 0);
            acc[1] = __builtin_amdgcn_mfma_f32_16x16x32_bf16(bP, aW1, acc[1], 0, 0, 0);
            acc[2] = __builtin_amdgcn_mfma_f32_16x16x32_bf16(bP, aW2, acc[2], 0, 0, 0);
            acc[3] = __builtin_amdgcn_mfma_f32_16x16x32_bf16(bP, aW3, acc[3], 0, 0, 0);
            if (j + 2 < 12)
                coords(sb + (j + 2) * 4, yxN, mrN,
                       qA00, qA01, qA10, qA11, wA00, wA01, wA10, wA11);
            if (j + 3 < 12) scal(sb + (j + 3) * 4, yxN, mrN);
        }
        {   // ODD: consume B (sample j+1); refill B with sample j+3
            const char* wj = wb + ((u32)(j + 1) << 12);
            v8s aW0 = *(const v8s*)(wj);
            v8s aW1 = *(const v8s*)(wj + 1024);
            v8s aW2 = *(const v8s*)(wj + 2048);
            v8s aW3 = *(const v8s*)(wj + 3072);
            v8s bP = blend(qB00, qB01, qB10, qB11, wB00, wB01, wB10, wB11);
            acc[0] = __builtin_amdgcn_mfma_f32_16x16x32_bf16(bP, aW0, acc[0], 0, 0, 0);
            acc[1] = __builtin_amdgcn_mfma_f32_16x16x32_bf16(bP, aW1, acc[1], 0, 0, 0);
            acc[2] = __builtin_amdgcn_mfma_f32_16x16x32_bf16(bP, aW2, acc[2], 0, 0, 0);
            acc[3] = __builtin_amdgcn_mfma_f32_16x16x32_bf16(bP, aW3, acc[3], 0, 0, 0);
            if (j + 3 < 12)
                coords(sb + (j + 3) * 4, yxN, mrN,
                       qB00, qB01, qB10, qB11, wB00, wB01, wB10, wB11);
            if (j + 4 < 12) scal(sb + (j + 4) * 4, yxN, mrN);
        }
    }

    // ---- in-block K reduction: sets 1,2 -> LDS; set 0 sums + writes y ----
    if (ks > 0) {
        #pragma unroll
        for (int m = 0; m < 4; ++m) R[ks - 1][m][ts] = acc[m];
    }
    __syncthreads();
    if (ks == 0) {
        #pragma unroll
        for (int m = 0; m < 4; ++m) {
            v4f s = acc[m];
            v4f r1 = R[0][m][ts];
            v4f r2 = R[1][m][ts];
            const int o = m * 16 + l15;
            const float bd = bdcn[o];
            const size_t idx = (size_t)(n * C_OUT + o) * HW + rem0 + wvs * 16 + lg * 4;
            *(float4*)&y[idx] = make_float4(s[0] + r1[0] + r2[0] + bd,
                                            s[1] + r1[1] + r2[1] + bd,
                                            s[2] + r1[2] + r2[2] + bd,
                                            s[3] + r1[3] + r2[3] + bd);
        }
    }
}

// ---------------------------------------------------------------------------
extern "C" void kernel_launch(void* const* d_in, const int* in_sizes, int n_in,
                              void* d_out, int out_size, void* d_ws, size_t ws_size,
                              hipStream_t stream) {
    const float* x  = (const float*)d_in[0];
    const float* ef = (const float*)d_in[1];
    const float* f1 = (const float*)d_in[2];
    const float* f2 = (const float*)d_in[3];
    const float* w0 = (const float*)d_in[4];
    const float* b0 = (const float*)d_in[5];
    const float* w1 = (const float*)d_in[6];
    const float* b1 = (const float*)d_in[7];
    const float* w2 = (const float*)d_in[8];
    const float* b2 = (const float*)d_in[9];
    const float* w3 = (const float*)d_in[10];
    const float* b3 = (const float*)d_in[11];
    const float* wd = (const float*)d_in[12];
    const float* bd = (const float*)d_in[13];
    float* y = (float*)d_out;
    char* wsb = (char*)d_ws;

    // Workspace (bytes), 16B-aligned; total ~75.4 MB. part buffer GONE.
    u16* catT  = (u16*)(wsb + 0);          // 18,874,368
    u16* h0T   = (u16*)(wsb + 18874368);   //  4,718,592
    u16* h1T   = (u16*)(wsb + 23592960);   //  4,718,592
    u16* h2T   = (u16*)(wsb + 28311552);   //  4,718,592
    u32* pairT = (u32*)(wsb + 33030144);   // 21,233,664
    u16* maskT = (u16*)(wsb + 54263808);   // 10,616,832
    u16* w0p   = (u16*)(wsb + 64880640);   //    294,912
    u16* w1p   = (u16*)(wsb + 65175552);   //     73,728
    u16* w2p   = (u16*)(wsb + 65249280);   //     73,728
    u16* w3p   = (u16*)(wsb + 65323008);   //    516,096
    u16* wdf   = (u16*)(wsb + 65839104);   //    147,456
    u16* xT    = (u16*)(wsb + 65986560);   //  9,437,184 -> ends 75,423,744

    prep_catT<<<dim3(NPIX / 64, 4), 256, 0, stream>>>(ef, f1, f2, catT);
    prep_xT  <<<dim3(NPIX / 64, 2), 256, 0, stream>>>(x, xT);
    pack_all <<<dim3(552960 / 256), 256, 0, stream>>>(
        w0, w0p, w1, w1p, w2, w2p, w3, w3p, wd, wdf);

    conv_mfma<256, 4, 64, true,  false, 1><<<dim3(768), 256, 0, stream>>>(
        catT, w0p, b0, 64, h0T, nullptr, nullptr);
    conv_mfma< 64, 1, 64, true,  false, 1><<<dim3(768), 256, 0, stream>>>(
        h0T, w1p, b1, 64, h1T, nullptr, nullptr);
    conv_mfma< 64, 1, 64, true,  false, 1><<<dim3(768), 256, 0, stream>>>(
        h1T, w2p, b2, 64, h2T, nullptr, nullptr);
    conv_mfma< 64, 1, 448, false, true, 7><<<dim3(NB * HH, 2), 256, 0, stream>>>(
        h2T, w3p, b3, 432, nullptr, pairT, maskT);

    dcn_fused<<<dim3(NPIX / 32), 384, 0, stream>>>(
        xT, f1, f2, pairT, maskT, wdf, bd, y);
}

// Round 11
// 133.652 us; speedup vs baseline: 1.1035x; 1.0092x over previous
//
#include <hip/hip_runtime.h>
#include <math.h>

#define NB 4
#define HH 96
#define WW 96
#define HW (HH*WW)
#define NPIX (NB*HW)
#define C_IN 128
#define C_OUT 64
#define DGRP 16
#define CG 8

typedef short v8s __attribute__((ext_vector_type(8)));
typedef float v4f __attribute__((ext_vector_type(4)));
typedef unsigned short u16;
typedef unsigned int u32;

__device__ __forceinline__ u16 f2bf(float x) {
    u32 u = __float_as_uint(x);
    u32 r = (u + 0x7FFFu + ((u >> 16) & 1u)) >> 16;   // RNE
    return (u16)r;
}
__device__ __forceinline__ float bf2f(u16 h) {
    return __uint_as_float(((u32)h) << 16);
}
__device__ __forceinline__ float lo_bf(u32 w) { return __uint_as_float(w << 16); }
__device__ __forceinline__ float hi_bf(u32 w) { return __uint_as_float(w & 0xFFFF0000u); }
__device__ __forceinline__ float ftanh(float x) {
    float e = __expf(2.0f * x);
    return 1.0f - 2.0f / (e + 1.0f);
}
__device__ __forceinline__ float fsigm(float x) {
    return 1.0f / (1.0f + __expf(-x));
}
__device__ __forceinline__ v8s u4_to_v8s(uint4 q) {
    union { uint4 q; v8s s; } u; u.q = q; return u.s;
}
// HW packed fp32->bf16 RNE: dst.lo16 = bf16(a), dst.hi16 = bf16(b).
__device__ __forceinline__ u32 cvtpk(float a, float b) {
    u32 r;
    asm("v_cvt_pk_bf16_f32 %0, %1, %2" : "=v"(r) : "v"(a), "v"(b));
    return r;
}
// async global->LDS, 16B per lane. Dest = wave-uniform base + lane*16 (m104),
// so per-lane lds ptr MUST be lane-linear. Source ptr is per-lane (m173).
typedef __attribute__((address_space(1))) const char gch1;
typedef __attribute__((address_space(3))) char ch3;
__device__ __forceinline__ void gload16(const void* g, void* l) {
    __builtin_amdgcn_global_load_lds((gch1*)g, (ch3*)l, 16, 0, 0);
}

// ---------------------------------------------------------------------------
// Prep 1: concat(extra_feat, flow1, flow2) -> pixel-major bf16 [NPIX][256]
// ---------------------------------------------------------------------------
__global__ __launch_bounds__(256) void prep_catT(
    const float* __restrict__ ef, const float* __restrict__ f1,
    const float* __restrict__ f2, u16* __restrict__ catT)
{
    __shared__ float T[64][65];
    const int t   = threadIdx.x;
    const int p   = blockIdx.x * 64;
    const int ch0 = blockIdx.y * 64;
    const int n   = p / HW;
    const int rem = p - n * HW;
    const int px  = t & 63;
    const int wv  = t >> 6;
    #pragma unroll
    for (int kk = 0; kk < 16; ++kk) {
        int chl = wv * 16 + kk;
        int ch  = ch0 + chl;
        float v = 0.f;
        if (ch < 192)      v = ef[(size_t)(n * 192 + ch) * HW + rem + px];
        else if (ch < 194) v = f1[(size_t)(n * 2 + (ch - 192)) * HW + rem + px];
        else if (ch < 196) v = f2[(size_t)(n * 2 + (ch - 194)) * HW + rem + px];
        T[chl][px] = v;
    }
    __syncthreads();
    const int s = t & 7;
    #pragma unroll
    for (int it = 0; it < 2; ++it) {
        int pxo = (t >> 3) + it * 32;
        u32 w0 = (u32)f2bf(T[s*8+0][pxo]) | ((u32)f2bf(T[s*8+1][pxo]) << 16);
        u32 w1 = (u32)f2bf(T[s*8+2][pxo]) | ((u32)f2bf(T[s*8+3][pxo]) << 16);
        u32 w2 = (u32)f2bf(T[s*8+4][pxo]) | ((u32)f2bf(T[s*8+5][pxo]) << 16);
        u32 w3 = (u32)f2bf(T[s*8+6][pxo]) | ((u32)f2bf(T[s*8+7][pxo]) << 16);
        *(uint4*)&catT[((size_t)(p + pxo)) * 256 + ch0 + s * 8] = make_uint4(w0, w1, w2, w3);
    }
}

// ---------------------------------------------------------------------------
// Prep: x [N,128,H,W] fp32 -> xT group-major bf16 [16 groups][NPIX][8]
// ---------------------------------------------------------------------------
__global__ __launch_bounds__(256) void prep_xT(
    const float* __restrict__ x, u16* __restrict__ xT)
{
    __shared__ float T[64][65];
    const int t   = threadIdx.x;
    const int p   = blockIdx.x * 64;
    const int ch0 = blockIdx.y * 64;
    const int n   = p / HW;
    const int rem = p - n * HW;
    const int px  = t & 63;
    const int wv  = t >> 6;
    #pragma unroll
    for (int kk = 0; kk < 16; ++kk) {
        int chl = wv * 16 + kk;
        T[chl][px] = x[(size_t)(n * C_IN + ch0 + chl) * HW + rem + px];
    }
    __syncthreads();
    const int s = t & 7;
    #pragma unroll
    for (int it = 0; it < 2; ++it) {
        int pxo = (t >> 3) + it * 32;
        u32 w0 = (u32)f2bf(T[s*8+0][pxo]) | ((u32)f2bf(T[s*8+1][pxo]) << 16);
        u32 w1 = (u32)f2bf(T[s*8+2][pxo]) | ((u32)f2bf(T[s*8+3][pxo]) << 16);
        u32 w2 = (u32)f2bf(T[s*8+4][pxo]) | ((u32)f2bf(T[s*8+5][pxo]) << 16);
        u32 w3 = (u32)f2bf(T[s*8+6][pxo]) | ((u32)f2bf(T[s*8+7][pxo]) << 16);
        *(uint4*)&xT[((size_t)(ch0 / 8 + s) * NPIX + (p + pxo)) * 8] = make_uint4(w0, w1, w2, w3);
    }
}

// ---------------------------------------------------------------------------
// ONE fused weight-pack kernel (+ zero-page init for conv gload staging).
// ---------------------------------------------------------------------------
__device__ __forceinline__ void pack_wf_one(
    const float* __restrict__ w, u16* __restrict__ wp,
    int Cout, int CoutPad, int CIN, int CIP, int idx)
{
    const int NKF = CIP / 32, NOG = CoutPad / 16;
    int c    = idx & 7;
    int ln   = (idx >> 3) & 63;
    int rest = idx >> 9;
    int og   = rest % NOG; rest /= NOG;
    int kfg  = rest % NKF;
    int tap  = rest / NKF;
    int l15 = ln & 15, lg = ln >> 4;
    int o  = og * 16 + l15;
    int ci = kfg * 32 + lg * 8 + c;
    float v = (o < Cout && ci < CIN) ? w[((size_t)o * CIN + ci) * 9 + tap] : 0.f;
    wp[idx] = f2bf(v);
}

__global__ __launch_bounds__(256) void pack_all(
    const float* __restrict__ w0, u16* __restrict__ w0p,
    const float* __restrict__ w1, u16* __restrict__ w1p,
    const float* __restrict__ w2, u16* __restrict__ w2p,
    const float* __restrict__ w3, u16* __restrict__ w3p,
    const float* __restrict__ wd, u16* __restrict__ wdf,
    uint4* __restrict__ zp)
{
    if (blockIdx.x == 0 && threadIdx.x < 32)
        zp[threadIdx.x] = make_uint4(0u, 0u, 0u, 0u);   // 512B zero page
    int idx = blockIdx.x * 256 + threadIdx.x;
    if (idx < 147456) { pack_wf_one(w0, w0p, 64, 64, 196, 256, idx); return; }
    idx -= 147456;
    if (idx < 36864)  { pack_wf_one(w1, w1p, 64, 64, 64, 64, idx); return; }
    idx -= 36864;
    if (idx < 36864)  { pack_wf_one(w2, w2p, 64, 64, 64, 64, idx); return; }
    idx -= 36864;
    if (idx < 258048) { pack_wf_one(w3, w3p, 432, 448, 64, 64, idx); return; }
    idx -= 258048;
    {   // pack_wdf
        int c  = idx & 7;
        int ln = (idx >> 3) & 63;
        int m  = (idx >> 9) & 3;
        int kk = idx >> 11;
        int l15 = ln & 15, lg = ln >> 4;
        int o = m * 16 + l15;
        int slot = kk * 4 + lg;
        int g = slot / 9, kt = slot - 9 * g;
        wdf[idx] = f2bf(wd[((size_t)(o * C_IN + g * CG + c)) * 9 + kt]);
    }
}

// ---------------------------------------------------------------------------
// MFMA implicit-GEMM 3x3 conv, 256 thr = 4 waves. Fragment-major weights.
// R11 (NOB==1): staging via global_load_lds width=16 (m97 pattern).
//   - LDS layout is linear in task order (COLS==NCOL==50): dest = task*16B.
//   - bank-swizzle moved to the SOURCE address (s' = s^(c&7), m173):
//     slot q still holds channel q^(c&7), MFMA reads unchanged.
//   - OOB taps read a 512B zero page with FULL exec (no leading-lane mask
//     hazard); only the task>=1200 tail is masked (lane 0 active => safe),
//     plus a 256B LDS pad per buffer as belt-and-braces.
//   - all addr math hoisted out of the chunk loop (chunk-invariant + ch*128).
// NOB>1 (conv3) keeps the register-staging path (staged once, amortized 7x).
// ---------------------------------------------------------------------------
template<int CIP, int NCHUNK, int OST, bool LRELU, bool TOUT, int NOB>
__global__ __launch_bounds__(256) void conv_mfma(
    const u16* __restrict__ inT,
    const u16* __restrict__ wp,
    const float* __restrict__ bias,
    int CoutReal,
    u16* __restrict__ outT,
    u32* __restrict__ pairT,
    u16* __restrict__ maskT,
    const char* __restrict__ zpc)
{
    constexpr int COLS  = (NOB > 1) ? 100 : 50;        // padded row stride
    constexpr int LTILE = 3 * COLS * 64;               // u16 units
    constexpr int LTILE_PAD = (NOB == 1) ? LTILE + 128 : LTILE;  // +256B pad
    constexpr int LSZ   = (NCHUNK > 1) ? 2 * LTILE_PAD : LTILE_PAD;
    constexpr int NKF   = CIP / 32;
    constexpr int NOG   = OST / 16;
    __shared__ __align__(16) u16 L[LSZ];

    const int t   = threadIdx.x;
    const int tb  = blockIdx.x;
    const int row = (NOB > 1) ? tb : (tb >> 1);
    const int p0  = (NOB > 1) ? 0 : (tb & 1) * 48;
    const int n   = row / HH;
    const int h   = row - n * HH;
    const int ln  = t & 63;
    const int wv  = t >> 6;          // 0..3
    const int l15 = ln & 15;
    const int lg  = ln >> 4;

    // ---- legacy register-staging (used by NOB>1 only) ----
    auto stage = [&](int ch, int buf) {
        const int cb = ch * 64;
        const int NCOL = (NOB > 1) ? 98 : 50;
        const int NTASK = 3 * NCOL * 8;
        u16* Lb = &L[buf * LTILE_PAD];
        #pragma unroll
        for (int it = 0; it < (NTASK + 255) / 256; ++it) {
            int task = it * 256 + t;
            if (task < NTASK) {
                int s  = task & 7;
                int cl = task >> 3;
                int r3 = cl / NCOL;
                int c  = cl - r3 * NCOL;
                int yy = h + r3 - 1;
                int xx = p0 + c - 1;
                uint4 v = make_uint4(0u, 0u, 0u, 0u);
                if ((unsigned)yy < HH && (unsigned)xx < WW)
                    v = *(const uint4*)&inT[((size_t)(n * HW + yy * WW + xx)) * CIP + cb + s * 8];
                *(uint4*)&Lb[(r3 * COLS + c) * 64 + ((s ^ (c & 7)) * 8)] = v;
            }
        }
    };

    if constexpr (NOB == 1) {
        // ---- chunk-invariant staging descriptors (1200 tasks, 5 slots) ----
        const char* inTc = (const char*)inT;
        auto mk = [&](int it) -> const char* {
            int task = it * 256 + t;
            if (task >= 1200) return zpc;
            int s  = task & 7;
            int cl = task >> 3;
            int r3 = cl / 50;
            int c  = cl - r3 * 50;
            int yy = h + r3 - 1;
            int xx = p0 + c - 1;
            bool v = ((unsigned)yy < HH) && ((unsigned)xx < WW);
            int sp = s ^ (c & 7);               // source-side bank swizzle
            u32 off = ((u32)(n * HW + yy * WW + xx) * (u32)CIP + (u32)(sp * 8)) * 2u;
            return v ? inTc + off : zpc;
        };
        const char* pb0 = mk(0);
        const char* pb1 = mk(1);
        const char* pb2 = mk(2);
        const char* pb3 = mk(3);
        const char* pb4 = mk(4);

        auto gstage = [&](int ch, int buf) {
            u16* Lb = &L[buf * LTILE_PAD];
            const u32 cb2 = (u32)ch * 128u;     // cb*2 bytes (cb = ch*64 u16)
            gload16(pb0 + cb2, &Lb[(u32)(0 * 256 + t) * 8u]);
            gload16(pb1 + cb2, &Lb[(u32)(1 * 256 + t) * 8u]);
            gload16(pb2 + cb2, &Lb[(u32)(2 * 256 + t) * 8u]);
            gload16(pb3 + cb2, &Lb[(u32)(3 * 256 + t) * 8u]);
            if (4 * 256 + t < 1200)
                gload16(pb4 + cb2, &Lb[(u32)(4 * 256 + t) * 8u]);
        };

        v4f acc[3];
        #pragma unroll
        for (int i = 0; i < 3; ++i) acc[i] = (v4f){0.f, 0.f, 0.f, 0.f};

        gstage(0, 0);
        for (int ch = 0; ch < NCHUNK; ++ch) {
            __syncthreads();                 // drains gload (vmcnt) + orders LDS
            if (ch + 1 < NCHUNK) gstage(ch + 1, (ch + 1) & 1);
            const u16* Lb = &L[(ch & 1) * LTILE_PAD];
            #pragma unroll
            for (int tap = 0; tap < 9; ++tap) {
                const int ty = tap / 3, tx = tap - ty * 3;
                #pragma unroll
                for (int kf = 0; kf < 2; ++kf) {
                    v8s b = *(const v8s*)&wp[((((size_t)tap * NKF + (ch * 2 + kf)) * NOG + wv) * 64 + ln) * 8];
                    #pragma unroll
                    for (int fm = 0; fm < 3; ++fm) {
                        int c = fm * 16 + l15 + tx;
                        v8s a = *(const v8s*)&Lb[(ty * COLS + c) * 64 + (((kf * 4 + lg) ^ (c & 7)) * 8)];
                        acc[fm] = __builtin_amdgcn_mfma_f32_16x16x32_bf16(a, b, acc[fm], 0, 0, 0);
                    }
                }
            }
        }

        int o = wv * 16 + l15;
        float bv = (o < CoutReal) ? bias[o] : 0.f;
        #pragma unroll
        for (int fm = 0; fm < 3; ++fm) {
            #pragma unroll
            for (int r = 0; r < 4; ++r) {
                int px = p0 + fm * 16 + lg * 4 + r;
                float v = acc[fm][r] + bv;
                if (LRELU) v = (v >= 0.f) ? v : 0.1f * v;
                outT[((size_t)(n * HW + h * WW + px)) * OST + o] = f2bf(v);
            }
        }
    } else {
        stage(0, 0);
        __syncthreads();
        const size_t gpix = (size_t)n * HW + h * WW;
        const int ob_lo = blockIdx.y * 4;
        const int ob_hi = (ob_lo + 4 < NOB) ? ob_lo + 4 : NOB;

        for (int ob = ob_lo; ob < ob_hi; ++ob) {
            const int obase = ob * 64 + wv * 16;
            if (obase >= 432) continue;

            v4f acc[6];
            #pragma unroll
            for (int i = 0; i < 6; ++i) acc[i] = (v4f){0.f, 0.f, 0.f, 0.f};

            #pragma unroll
            for (int tap = 0; tap < 9; ++tap) {
                const int ty = tap / 3, tx = tap - ty * 3;
                #pragma unroll
                for (int kf = 0; kf < 2; ++kf) {
                    v8s bw = *(const v8s*)&wp[((((size_t)tap * NKF + kf) * NOG + (ob * 4 + wv)) * 64 + ln) * 8];
                    #pragma unroll
                    for (int fm = 0; fm < 6; ++fm) {
                        int c = fm * 16 + l15 + tx;
                        v8s a = *(const v8s*)&L[(ty * COLS + c) * 64 + (((kf * 4 + lg) ^ (c & 7)) * 8)];
                        acc[fm] = __builtin_amdgcn_mfma_f32_16x16x32_bf16(bw, a, acc[fm], 0, 0, 0);
                    }
                }
            }

            float bv[4];
            #pragma unroll
            for (int r = 0; r < 4; ++r) bv[r] = bias[obase + lg * 4 + r];

            if (obase < 288) {
                const int pr = (obase + lg * 4) >> 1;
                #pragma unroll
                for (int fm = 0; fm < 6; ++fm) {
                    const size_t pix = gpix + fm * 16 + l15;
                    u32 v0 = (u32)f2bf(acc[fm][0] + bv[0]) | ((u32)f2bf(acc[fm][1] + bv[1]) << 16);
                    u32 v1 = (u32)f2bf(acc[fm][2] + bv[2]) | ((u32)f2bf(acc[fm][3] + bv[3]) << 16);
                    pairT[(size_t)pr * NPIX + pix]       = v0;
                    pairT[(size_t)(pr + 1) * NPIX + pix] = v1;
                }
            } else {
                #pragma unroll
                for (int fm = 0; fm < 6; ++fm) {
                    const size_t pix = gpix + fm * 16 + l15;
                    #pragma unroll
                    for (int r = 0; r < 4; ++r) {
                        int mch = obase + lg * 4 + r - 288;
                        maskT[(size_t)mch * NPIX + pix] = f2bf(acc[fm][r] + bv[r]);
                    }
                }
            }
        }
    }
}

// ---------------------------------------------------------------------------
// Fused DCN sample+GEMM. IN-BLOCK K-split (R10, proven: combined 55.9us vs
// R6's ~60.7 split; WRITE 27.6->9.2MB). Block = 32 px x 3 sets (384 thr).
// XCD swizzle (FETCH 55->21.7MB, proven R5/R6).
// ---------------------------------------------------------------------------
__global__ __launch_bounds__(384) void dcn_fused(
    const u16* __restrict__ xT,     // [16][NPIX][8] bf16
    const float* __restrict__ f1,
    const float* __restrict__ f2,
    const u32*  __restrict__ pairT, // [144][NPIX] raw bf16 offset pairs
    const u16*  __restrict__ maskT, // [144][NPIX] raw bf16 mask
    const u16*  __restrict__ wdf,   // [36][4][64][8] bf16 fragment-major
    const float* __restrict__ bdcn,
    float* __restrict__ y)          // [N,64,H,W] fp32
{
    __shared__ __align__(16) v4f R[2][4][128];   // 16KB: sets 1,2 partials

    const int t    = threadIdx.x;                  // 0..383
    const int xb   = blockIdx.x;                   // 0..1151
    const int xw   = (xb & 7) * 144 + (xb >> 3);   // XCD-contiguous tile id
    const int p0   = xw * 32;
    const int w6   = t >> 6;                       // wave 0..5
    const int ks   = w6 >> 1;                      // K-split set 0..2
    const int wvs  = w6 & 1;                       // wave within set 0..1
    const int ln   = t & 63;
    const int l15  = ln & 15;
    const int lg   = ln >> 4;
    const int ts   = wvs * 64 + ln;                // 0..127, id within set
    const int n    = p0 / HW;
    const int rem0 = p0 - n * HW;
    const int p    = p0 + wvs * 16 + l15;   // this thread's sampling pixel
    const int rem  = rem0 + wvs * 16 + l15;
    const int h    = rem / WW;
    const int w    = rem - h * WW;

    const char* pTc = (const char*)pairT;
    const char* mTc = (const char*)maskT;
    const char* xTc = (const char*)xT;
    const u32 p4   = (u32)p << 2;
    const u32 p2   = (u32)p << 1;
    const u32 nb16 = (u32)(n * HW) << 4;           // xT image base, 16B/pixel

    // flows + grid bases hoisted (f?yh = flow_y + h, f?xw = flow_x + w)
    const float f1yh = f1[(size_t)(n * 2 + 1) * HW + rem] + (float)h;
    const float f1xw = f1[(size_t)(n * 2 + 0) * HW + rem] + (float)w;
    const float f2yh = f2[(size_t)(n * 2 + 1) * HW + rem] + (float)h;
    const float f2xw = f2[(size_t)(n * 2 + 0) * HW + rem] + (float)w;

    auto scal = [&](int sl, u32& yx, float& mr) {
        yx = *(const u32*)(pTc + ((u32)sl * (u32)(NPIX * 4) + p4));
        mr = bf2f(*(const u16*)(mTc + ((u32)sl * (u32)(NPIX * 2) + p2)));
    };

    // coords: bilinear weights (mask folded) + issue 4 gathers
    auto coords = [&](int sl, u32 yx, float mr,
                      uint4& q00, uint4& q01, uint4& q10, uint4& q11,
                      float& w00, float& w01, float& w10, float& w11) {
        const int g  = (sl * 57) >> 9;            // sl/9 exact for sl<144
        const int kt = sl - 9 * g;
        const int ky = (kt * 11) >> 5;            // kt/3 for kt<9
        const int kx = kt - 3 * ky;
        const float fy = (g < 8) ? f1yh : f2yh;
        const float fx = (g < 8) ? f1xw : f2xw;
        const float py  = 10.0f * ftanh(lo_bf(yx)) + (fy + (float)(ky - 1));
        const float pxx = 10.0f * ftanh(hi_bf(yx)) + (fx + (float)(kx - 1));
        const float m   = fsigm(mr);

        const float y0f = floorf(py), x0f = floorf(pxx);
        const int   iy0 = (int)y0f,   ix0 = (int)x0f;
        const float wy = py - y0f, wx = pxx - x0f;
        const bool v0y = ((unsigned)iy0 < HH);
        const bool v1y = ((unsigned)(iy0 + 1) < HH);
        const bool v0x = ((unsigned)ix0 < WW);
        const bool v1x = ((unsigned)(ix0 + 1) < WW);
        const float wy0m = (1.0f - wy) * m, wy1m = wy * m;
        w00 = (v0y && v0x) ? wy0m * (1.0f - wx) : 0.0f;
        w01 = (v0y && v1x) ? wy0m * wx          : 0.0f;
        w10 = (v1y && v0x) ? wy1m * (1.0f - wx) : 0.0f;
        w11 = (v1y && v1x) ? wy1m * wx          : 0.0f;

        const int iy0c = min(max(iy0, 0), HH - 1);
        const int iy1c = min(max(iy0 + 1, 0), HH - 1);
        const int ix0c = min(max(ix0, 0), WW - 1);
        const int ix1c = min(max(ix0 + 1, 0), WW - 1);
        const u32 gof = (u32)g * (u32)(NPIX * 16) + nb16;
        const u32 r0  = gof + (u32)iy0c * (u32)(WW * 16);
        const u32 r1  = gof + (u32)iy1c * (u32)(WW * 16);
        const u32 c0  = (u32)ix0c << 4;
        const u32 c1  = (u32)ix1c << 4;
        q00 = *(const uint4*)(xTc + (r0 + c0));
        q01 = *(const uint4*)(xTc + (r0 + c1));
        q10 = *(const uint4*)(xTc + (r1 + c0));
        q11 = *(const uint4*)(xTc + (r1 + c1));
    };

    auto blend = [&](const uint4& q00, const uint4& q01,
                     const uint4& q10, const uint4& q11,
                     float w00, float w01, float w10, float w11) -> v8s {
        u32 pv0 = cvtpk(
            w00*lo_bf(q00.x) + w01*lo_bf(q01.x) + w10*lo_bf(q10.x) + w11*lo_bf(q11.x),
            w00*hi_bf(q00.x) + w01*hi_bf(q01.x) + w10*hi_bf(q10.x) + w11*hi_bf(q11.x));
        u32 pv1 = cvtpk(
            w00*lo_bf(q00.y) + w01*lo_bf(q01.y) + w10*lo_bf(q10.y) + w11*lo_bf(q11.y),
            w00*hi_bf(q00.y) + w01*hi_bf(q01.y) + w10*hi_bf(q10.y) + w11*hi_bf(q11.y));
        u32 pv2 = cvtpk(
            w00*lo_bf(q00.z) + w01*lo_bf(q01.z) + w10*lo_bf(q10.z) + w11*lo_bf(q11.z),
            w00*hi_bf(q00.z) + w01*hi_bf(q01.z) + w10*hi_bf(q10.z) + w11*hi_bf(q11.z));
        u32 pv3 = cvtpk(
            w00*lo_bf(q00.w) + w01*lo_bf(q01.w) + w10*lo_bf(q10.w) + w11*lo_bf(q11.w),
            w00*hi_bf(q00.w) + w01*hi_bf(q01.w) + w10*hi_bf(q10.w) + w11*hi_bf(q11.w));
        return u4_to_v8s(make_uint4(pv0, pv1, pv2, pv3));
    };

    v4f acc[4];
    #pragma unroll
    for (int i = 0; i < 4; ++i) acc[i] = (v4f){0.f, 0.f, 0.f, 0.f};

    const int cc0 = ks * 12;
    const int sb  = cc0 * 4 + lg;           // slot of sample i = sb + 4*i
    const char* wb = (const char*)wdf + ((u32)cc0 << 12) + ((u32)ln << 4);

    // ---- pipeline state (named, no runtime-indexed arrays) ----
    uint4 qA00, qA01, qA10, qA11;  float wA00, wA01, wA10, wA11;
    uint4 qB00, qB01, qB10, qB11;  float wB00, wB01, wB10, wB11;
    u32 yxN; float mrN;

    {   // prologue: fill A (sample 0), B (sample 1); preload scalars for 2
        u32 yx; float mr;
        scal(sb, yx, mr);
        coords(sb, yx, mr, qA00, qA01, qA10, qA11, wA00, wA01, wA10, wA11);
        scal(sb + 4, yx, mr);
        coords(sb + 4, yx, mr, qB00, qB01, qB10, qB11, wB00, wB01, wB10, wB11);
        scal(sb + 8, yxN, mrN);
    }

    #pragma unroll 1
    for (int j = 0; j < 12; j += 2) {
        {   // EVEN: consume A (sample j); refill A with sample j+2
            const char* wj = wb + ((u32)j << 12);
            v8s aW0 = *(const v8s*)(wj);
            v8s aW1 = *(const v8s*)(wj + 1024);
            v8s aW2 = *(const v8s*)(wj + 2048);
            v8s aW3 = *(const v8s*)(wj + 3072);
            v8s bP = blend(qA00, qA01, qA10, qA11, wA00, wA01, wA10, wA11);
            acc[0] = __builtin_amdgcn_mfma_f32_16x16x32_bf16(bP, aW0, acc[0], 0, 0, 0);
            acc[1] = __builtin_amdgcn_mfma_f32_16x16x32_bf16(bP, aW1, acc[1], 0, 0, 0);
            acc[2] = __builtin_amdgcn_mfma_f32_16x16x32_bf16(bP, aW2, acc[2], 0, 0, 0);
            acc[3] = __builtin_amdgcn_mfma_f32_16x16x32_bf16(bP, aW3, acc[3], 0, 0, 0);
            if (j + 2 < 12)
                coords(sb + (j + 2) * 4, yxN, mrN,
                       qA00, qA01, qA10, qA11, wA00, wA01, wA10, wA11);
            if (j + 3 < 12) scal(sb + (j + 3) * 4, yxN, mrN);
        }
        {   // ODD: consume B (sample j+1); refill B with sample j+3
            const char* wj = wb + ((u32)(j + 1) << 12);
            v8s aW0 = *(const v8s*)(wj);
            v8s aW1 = *(const v8s*)(wj + 1024);
            v8s aW2 = *(const v8s*)(wj + 2048);
            v8s aW3 = *(const v8s*)(wj + 3072);
            v8s bP = blend(qB00, qB01, qB10, qB11, wB00, wB01, wB10, wB11);
            acc[0] = __builtin_amdgcn_mfma_f32_16x16x32_bf16(bP, aW0, acc[0], 0, 0, 0);
            acc[1] = __builtin_amdgcn_mfma_f32_16x16x32_bf16(bP, aW1, acc[1], 0, 0, 0);
            acc[2] = __builtin_amdgcn_mfma_f32_16x16x32_bf16(bP, aW2, acc[2], 0, 0, 0);
            acc[3] = __builtin_amdgcn_mfma_f32_16x16x32_bf16(bP, aW3, acc[3], 0, 0, 0);
            if (j + 3 < 12)
                coords(sb + (j + 3) * 4, yxN, mrN,
                       qB00, qB01, qB10, qB11, wB00, wB01, wB10, wB11);
            if (j + 4 < 12) scal(sb + (j + 4) * 4, yxN, mrN);
        }
    }

    // ---- in-block K reduction: sets 1,2 -> LDS; set 0 sums + writes y ----
    if (ks > 0) {
        #pragma unroll
        for (int m = 0; m < 4; ++m) R[ks - 1][m][ts] = acc[m];
    }
    __syncthreads();
    if (ks == 0) {
        #pragma unroll
        for (int m = 0; m < 4; ++m) {
            v4f s = acc[m];
            v4f r1 = R[0][m][ts];
            v4f r2 = R[1][m][ts];
            const int o = m * 16 + l15;
            const float bd = bdcn[o];
            const size_t idx = (size_t)(n * C_OUT + o) * HW + rem0 + wvs * 16 + lg * 4;
            *(float4*)&y[idx] = make_float4(s[0] + r1[0] + r2[0] + bd,
                                            s[1] + r1[1] + r2[1] + bd,
                                            s[2] + r1[2] + r2[2] + bd,
                                            s[3] + r1[3] + r2[3] + bd);
        }
    }
}

// ---------------------------------------------------------------------------
extern "C" void kernel_launch(void* const* d_in, const int* in_sizes, int n_in,
                              void* d_out, int out_size, void* d_ws, size_t ws_size,
                              hipStream_t stream) {
    const float* x  = (const float*)d_in[0];
    const float* ef = (const float*)d_in[1];
    const float* f1 = (const float*)d_in[2];
    const float* f2 = (const float*)d_in[3];
    const float* w0 = (const float*)d_in[4];
    const float* b0 = (const float*)d_in[5];
    const float* w1 = (const float*)d_in[6];
    const float* b1 = (const float*)d_in[7];
    const float* w2 = (const float*)d_in[8];
    const float* b2 = (const float*)d_in[9];
    const float* w3 = (const float*)d_in[10];
    const float* b3 = (const float*)d_in[11];
    const float* wd = (const float*)d_in[12];
    const float* bd = (const float*)d_in[13];
    float* y = (float*)d_out;
    char* wsb = (char*)d_ws;

    // Workspace (bytes), 16B-aligned; total ~75.4 MB + 512B zero page.
    u16* catT  = (u16*)(wsb + 0);          // 18,874,368
    u16* h0T   = (u16*)(wsb + 18874368);   //  4,718,592
    u16* h1T   = (u16*)(wsb + 23592960);   //  4,718,592
    u16* h2T   = (u16*)(wsb + 28311552);   //  4,718,592
    u32* pairT = (u32*)(wsb + 33030144);   // 21,233,664
    u16* maskT = (u16*)(wsb + 54263808);   // 10,616,832
    u16* w0p   = (u16*)(wsb + 64880640);   //    294,912
    u16* w1p   = (u16*)(wsb + 65175552);   //     73,728
    u16* w2p   = (u16*)(wsb + 65249280);   //     73,728
    u16* w3p   = (u16*)(wsb + 65323008);   //    516,096
    u16* wdf   = (u16*)(wsb + 65839104);   //    147,456
    u16* xT    = (u16*)(wsb + 65986560);   //  9,437,184 -> ends 75,423,744
    char* zp   = (wsb + 75423744);         //        512 (zero page)

    prep_catT<<<dim3(NPIX / 64, 4), 256, 0, stream>>>(ef, f1, f2, catT);
    prep_xT  <<<dim3(NPIX / 64, 2), 256, 0, stream>>>(x, xT);
    pack_all <<<dim3(552960 / 256), 256, 0, stream>>>(
        w0, w0p, w1, w1p, w2, w2p, w3, w3p, wd, wdf, (uint4*)zp);

    conv_mfma<256, 4, 64, true,  false, 1><<<dim3(768), 256, 0, stream>>>(
        catT, w0p, b0, 64, h0T, nullptr, nullptr, zp);
    conv_mfma< 64, 1, 64, true,  false, 1><<<dim3(768), 256, 0, stream>>>(
        h0T, w1p, b1, 64, h1T, nullptr, nullptr, zp);
    conv_mfma< 64, 1, 64, true,  false, 1><<<dim3(768), 256, 0, stream>>>(
        h1T, w2p, b2, 64, h2T, nullptr, nullptr, zp);
    conv_mfma< 64, 1, 448, false, true, 7><<<dim3(NB * HH, 2), 256, 0, stream>>>(
        h2T, w3p, b3, 432, nullptr, pairT, maskT, zp);

    dcn_fused<<<dim3(NPIX / 32), 384, 0, stream>>>(
        xT, f1, f2, pairT, maskT, wdf, bd, y);
}

// Round 13
// 117.256 us; speedup vs baseline: 1.2578x; 1.1398x over previous
//
#include <hip/hip_runtime.h>
#include <math.h>

#define NB 4
#define HH 96
#define WW 96
#define HW (HH*WW)
#define NPIX (NB*HW)
#define C_IN 128
#define C_OUT 64
#define DGRP 16
#define CG 8

typedef short v8s __attribute__((ext_vector_type(8)));
typedef float v4f __attribute__((ext_vector_type(4)));
typedef unsigned short u16;
typedef unsigned int u32;

__device__ __forceinline__ u16 f2bf(float x) {
    u32 u = __float_as_uint(x);
    u32 r = (u + 0x7FFFu + ((u >> 16) & 1u)) >> 16;   // RNE
    return (u16)r;
}
__device__ __forceinline__ float bf2f(u16 h) {
    return __uint_as_float(((u32)h) << 16);
}
__device__ __forceinline__ float lo_bf(u32 w) { return __uint_as_float(w << 16); }
__device__ __forceinline__ float hi_bf(u32 w) { return __uint_as_float(w & 0xFFFF0000u); }
__device__ __forceinline__ float ftanh(float x) {
    float e = __expf(2.0f * x);
    return 1.0f - 2.0f / (e + 1.0f);
}
__device__ __forceinline__ float fsigm(float x) {
    return 1.0f / (1.0f + __expf(-x));
}
__device__ __forceinline__ v8s u4_to_v8s(uint4 q) {
    union { uint4 q; v8s s; } u; u.q = q; return u.s;
}
// HW packed fp32->bf16 RNE: dst.lo16 = bf16(a), dst.hi16 = bf16(b).
__device__ __forceinline__ u32 cvtpk(float a, float b) {
    u32 r;
    asm("v_cvt_pk_bf16_f32 %0, %1, %2" : "=v"(r) : "v"(a), "v"(b));
    return r;
}
// async global->LDS, 16B per lane (dest lane-linear, src per-lane; m104/m173)
typedef __attribute__((address_space(1))) const char gch1;
typedef __attribute__((address_space(3))) char ch3;
__device__ __forceinline__ void gload16(const void* g, void* l) {
    __builtin_amdgcn_global_load_lds((gch1*)g, (ch3*)l, 16, 0, 0);
}

// ---------------------------------------------------------------------------
// ONE fused prep dispatch: catT (2304 blk = 576x4) + xT (1152 blk = 576x2) +
// weight-pack (2160 blk). Total 5616.
// R12 crash post-mortem: decode used 2304 pixel-tiles/section but NPIX/64 =
// 576 -- p overran 4x -> GPU fault. Fixed: /576 decode.
// ---------------------------------------------------------------------------
__device__ __forceinline__ void pack_wf_one(
    const float* __restrict__ w, u16* __restrict__ wp,
    int Cout, int CoutPad, int CIN, int CIP, int idx)
{
    const int NKF = CIP / 32, NOG = CoutPad / 16;
    int c    = idx & 7;
    int ln   = (idx >> 3) & 63;
    int rest = idx >> 9;
    int og   = rest % NOG; rest /= NOG;
    int kfg  = rest % NKF;
    int tap  = rest / NKF;
    int l15 = ln & 15, lg = ln >> 4;
    int o  = og * 16 + l15;
    int ci = kfg * 32 + lg * 8 + c;
    float v = (o < Cout && ci < CIN) ? w[((size_t)o * CIN + ci) * 9 + tap] : 0.f;
    wp[idx] = f2bf(v);
}

__global__ __launch_bounds__(256) void prep_all(
    const float* __restrict__ ef, const float* __restrict__ f1,
    const float* __restrict__ f2, const float* __restrict__ x,
    u16* __restrict__ catT, u16* __restrict__ xT,
    const float* __restrict__ w0, u16* __restrict__ w0p,
    const float* __restrict__ w1, u16* __restrict__ w1p,
    const float* __restrict__ w2, u16* __restrict__ w2p,
    const float* __restrict__ w3, u16* __restrict__ w3p,
    const float* __restrict__ wd, u16* __restrict__ wdf,
    uint4* __restrict__ zp)
{
    __shared__ float T[64][65];
    const int t = threadIdx.x;
    int bid = blockIdx.x;

    if (bid < 2304) {              // ---- catT: concat -> pixel-major bf16 ----
        const int by  = bid / 576, bx = bid - by * 576;
        const int p   = bx * 64;
        const int ch0 = by * 64;
        const int n   = p / HW;
        const int rem = p - n * HW;
        const int px  = t & 63;
        const int wv  = t >> 6;
        #pragma unroll
        for (int kk = 0; kk < 16; ++kk) {
            int chl = wv * 16 + kk;
            int ch  = ch0 + chl;
            float v = 0.f;
            if (ch < 192)      v = ef[(size_t)(n * 192 + ch) * HW + rem + px];
            else if (ch < 194) v = f1[(size_t)(n * 2 + (ch - 192)) * HW + rem + px];
            else if (ch < 196) v = f2[(size_t)(n * 2 + (ch - 194)) * HW + rem + px];
            T[chl][px] = v;
        }
        __syncthreads();
        const int s = t & 7;
        #pragma unroll
        for (int it = 0; it < 2; ++it) {
            int pxo = (t >> 3) + it * 32;
            u32 q0 = (u32)f2bf(T[s*8+0][pxo]) | ((u32)f2bf(T[s*8+1][pxo]) << 16);
            u32 q1 = (u32)f2bf(T[s*8+2][pxo]) | ((u32)f2bf(T[s*8+3][pxo]) << 16);
            u32 q2 = (u32)f2bf(T[s*8+4][pxo]) | ((u32)f2bf(T[s*8+5][pxo]) << 16);
            u32 q3 = (u32)f2bf(T[s*8+6][pxo]) | ((u32)f2bf(T[s*8+7][pxo]) << 16);
            *(uint4*)&catT[((size_t)(p + pxo)) * 256 + ch0 + s * 8] = make_uint4(q0, q1, q2, q3);
        }
        return;
    }
    bid -= 2304;
    if (bid < 1152) {              // ---- xT: x -> group-major bf16 ----
        const int by  = bid / 576, bx = bid - by * 576;
        const int p   = bx * 64;
        const int ch0 = by * 64;
        const int n   = p / HW;
        const int rem = p - n * HW;
        const int px  = t & 63;
        const int wv  = t >> 6;
        #pragma unroll
        for (int kk = 0; kk < 16; ++kk) {
            int chl = wv * 16 + kk;
            T[chl][px] = x[(size_t)(n * C_IN + ch0 + chl) * HW + rem + px];
        }
        __syncthreads();
        const int s = t & 7;
        #pragma unroll
        for (int it = 0; it < 2; ++it) {
            int pxo = (t >> 3) + it * 32;
            u32 q0 = (u32)f2bf(T[s*8+0][pxo]) | ((u32)f2bf(T[s*8+1][pxo]) << 16);
            u32 q1 = (u32)f2bf(T[s*8+2][pxo]) | ((u32)f2bf(T[s*8+3][pxo]) << 16);
            u32 q2 = (u32)f2bf(T[s*8+4][pxo]) | ((u32)f2bf(T[s*8+5][pxo]) << 16);
            u32 q3 = (u32)f2bf(T[s*8+6][pxo]) | ((u32)f2bf(T[s*8+7][pxo]) << 16);
            *(uint4*)&xT[((size_t)(ch0 / 8 + s) * NPIX + (p + pxo)) * 8] = make_uint4(q0, q1, q2, q3);
        }
        return;
    }
    bid -= 1152;                   // ---- weight pack (2160 blocks) ----
    if (bid == 0 && t < 32)
        zp[t] = make_uint4(0u, 0u, 0u, 0u);   // 512B zero page
    int idx = bid * 256 + t;
    if (idx < 147456) { pack_wf_one(w0, w0p, 64, 64, 196, 256, idx); return; }
    idx -= 147456;
    if (idx < 36864)  { pack_wf_one(w1, w1p, 64, 64, 64, 64, idx); return; }
    idx -= 36864;
    if (idx < 36864)  { pack_wf_one(w2, w2p, 64, 64, 64, 64, idx); return; }
    idx -= 36864;
    if (idx < 258048) { pack_wf_one(w3, w3p, 432, 448, 64, 64, idx); return; }
    idx -= 258048;
    {   // pack_wdf
        int c  = idx & 7;
        int ln = (idx >> 3) & 63;
        int m  = (idx >> 9) & 3;
        int kk = idx >> 11;
        int l15 = ln & 15, lg = ln >> 4;
        int o = m * 16 + l15;
        int slot = kk * 4 + lg;
        int g = slot / 9, kt = slot - 9 * g;
        wdf[idx] = f2bf(wd[((size_t)(o * C_IN + g * CG + c)) * 9 + kt]);
    }
}

// ---------------------------------------------------------------------------
// MFMA implicit-GEMM 3x3 conv, 256 thr = 4 waves. Fragment-major weights.
// NOB==1: gload_lds staging (R11). conv1 (CIP=256) skips the dead
// (ch==3, kf==1) block -- channels 224..255 are all zero-padded weights.
// ---------------------------------------------------------------------------
template<int CIP, int NCHUNK, int OST, bool LRELU, bool TOUT, int NOB>
__global__ __launch_bounds__(256) void conv_mfma(
    const u16* __restrict__ inT,
    const u16* __restrict__ wp,
    const float* __restrict__ bias,
    int CoutReal,
    u16* __restrict__ outT,
    u32* __restrict__ pairT,
    u16* __restrict__ maskT,
    const char* __restrict__ zpc)
{
    constexpr int COLS  = (NOB > 1) ? 100 : 50;        // padded row stride
    constexpr int LTILE = 3 * COLS * 64;               // u16 units
    constexpr int LTILE_PAD = (NOB == 1) ? LTILE + 128 : LTILE;  // +256B pad
    constexpr int LSZ   = (NCHUNK > 1) ? 2 * LTILE_PAD : LTILE_PAD;
    constexpr int NKF   = CIP / 32;
    constexpr int NOG   = OST / 16;
    __shared__ __align__(16) u16 L[LSZ];

    const int t   = threadIdx.x;
    const int tb  = blockIdx.x;
    const int row = (NOB > 1) ? tb : (tb >> 1);
    const int p0  = (NOB > 1) ? 0 : (tb & 1) * 48;
    const int n   = row / HH;
    const int h   = row - n * HH;
    const int ln  = t & 63;
    const int wv  = t >> 6;          // 0..3
    const int l15 = ln & 15;
    const int lg  = ln >> 4;

    // ---- legacy register-staging (used by NOB>1 only) ----
    auto stage = [&](int ch, int buf) {
        const int cb = ch * 64;
        const int NCOL = (NOB > 1) ? 98 : 50;
        const int NTASK = 3 * NCOL * 8;
        u16* Lb = &L[buf * LTILE_PAD];
        #pragma unroll
        for (int it = 0; it < (NTASK + 255) / 256; ++it) {
            int task = it * 256 + t;
            if (task < NTASK) {
                int s  = task & 7;
                int cl = task >> 3;
                int r3 = cl / NCOL;
                int c  = cl - r3 * NCOL;
                int yy = h + r3 - 1;
                int xx = p0 + c - 1;
                uint4 v = make_uint4(0u, 0u, 0u, 0u);
                if ((unsigned)yy < HH && (unsigned)xx < WW)
                    v = *(const uint4*)&inT[((size_t)(n * HW + yy * WW + xx)) * CIP + cb + s * 8];
                *(uint4*)&Lb[(r3 * COLS + c) * 64 + ((s ^ (c & 7)) * 8)] = v;
            }
        }
    };

    if constexpr (NOB == 1) {
        // ---- chunk-invariant staging descriptors (1200 tasks, 5 slots) ----
        const char* inTc = (const char*)inT;
        auto mk = [&](int it) -> const char* {
            int task = it * 256 + t;
            if (task >= 1200) return zpc;
            int s  = task & 7;
            int cl = task >> 3;
            int r3 = cl / 50;
            int c  = cl - r3 * 50;
            int yy = h + r3 - 1;
            int xx = p0 + c - 1;
            bool v = ((unsigned)yy < HH) && ((unsigned)xx < WW);
            int sp = s ^ (c & 7);               // source-side bank swizzle
            u32 off = ((u32)(n * HW + yy * WW + xx) * (u32)CIP + (u32)(sp * 8)) * 2u;
            return v ? inTc + off : zpc;
        };
        const char* pb0 = mk(0);
        const char* pb1 = mk(1);
        const char* pb2 = mk(2);
        const char* pb3 = mk(3);
        const char* pb4 = mk(4);

        auto gstage = [&](int ch, int buf) {
            u16* Lb = &L[buf * LTILE_PAD];
            const u32 cb2 = (u32)ch * 128u;     // cb*2 bytes
            gload16(pb0 + cb2, &Lb[(u32)(0 * 256 + t) * 8u]);
            gload16(pb1 + cb2, &Lb[(u32)(1 * 256 + t) * 8u]);
            gload16(pb2 + cb2, &Lb[(u32)(2 * 256 + t) * 8u]);
            gload16(pb3 + cb2, &Lb[(u32)(3 * 256 + t) * 8u]);
            if (4 * 256 + t < 1200)
                gload16(pb4 + cb2, &Lb[(u32)(4 * 256 + t) * 8u]);
        };

        v4f acc[3];
        #pragma unroll
        for (int i = 0; i < 3; ++i) acc[i] = (v4f){0.f, 0.f, 0.f, 0.f};

        gstage(0, 0);
        for (int ch = 0; ch < NCHUNK; ++ch) {
            __syncthreads();                 // drains gload + orders LDS
            if (ch + 1 < NCHUNK) gstage(ch + 1, (ch + 1) & 1);
            const u16* Lb = &L[(ch & 1) * LTILE_PAD];
            #pragma unroll
            for (int tap = 0; tap < 9; ++tap) {
                const int ty = tap / 3, tx = tap - ty * 3;
                #pragma unroll
                for (int kf = 0; kf < 2; ++kf) {
                    // conv1 dead block: ch3/kf1 = channels 224..255, all zero
                    if (CIP == 256 && ch == 3 && kf == 1) continue;
                    v8s b = *(const v8s*)&wp[((((size_t)tap * NKF + (ch * 2 + kf)) * NOG + wv) * 64 + ln) * 8];
                    #pragma unroll
                    for (int fm = 0; fm < 3; ++fm) {
                        int c = fm * 16 + l15 + tx;
                        v8s a = *(const v8s*)&Lb[(ty * COLS + c) * 64 + (((kf * 4 + lg) ^ (c & 7)) * 8)];
                        acc[fm] = __builtin_amdgcn_mfma_f32_16x16x32_bf16(a, b, acc[fm], 0, 0, 0);
                    }
                }
            }
        }

        int o = wv * 16 + l15;
        float bv = (o < CoutReal) ? bias[o] : 0.f;
        #pragma unroll
        for (int fm = 0; fm < 3; ++fm) {
            #pragma unroll
            for (int r = 0; r < 4; ++r) {
                int px = p0 + fm * 16 + lg * 4 + r;
                float v = acc[fm][r] + bv;
                if (LRELU) v = (v >= 0.f) ? v : 0.1f * v;
                outT[((size_t)(n * HW + h * WW + px)) * OST + o] = f2bf(v);
            }
        }
    } else {
        stage(0, 0);
        __syncthreads();
        const size_t gpix = (size_t)n * HW + h * WW;
        const int ob_lo = blockIdx.y * 4;
        const int ob_hi = (ob_lo + 4 < NOB) ? ob_lo + 4 : NOB;

        for (int ob = ob_lo; ob < ob_hi; ++ob) {
            const int obase = ob * 64 + wv * 16;
            if (obase >= 432) continue;

            v4f acc[6];
            #pragma unroll
            for (int i = 0; i < 6; ++i) acc[i] = (v4f){0.f, 0.f, 0.f, 0.f};

            #pragma unroll
            for (int tap = 0; tap < 9; ++tap) {
                const int ty = tap / 3, tx = tap - ty * 3;
                #pragma unroll
                for (int kf = 0; kf < 2; ++kf) {
                    v8s bw = *(const v8s*)&wp[((((size_t)tap * NKF + kf) * NOG + (ob * 4 + wv)) * 64 + ln) * 8];
                    #pragma unroll
                    for (int fm = 0; fm < 6; ++fm) {
                        int c = fm * 16 + l15 + tx;
                        v8s a = *(const v8s*)&L[(ty * COLS + c) * 64 + (((kf * 4 + lg) ^ (c & 7)) * 8)];
                        acc[fm] = __builtin_amdgcn_mfma_f32_16x16x32_bf16(bw, a, acc[fm], 0, 0, 0);
                    }
                }
            }

            float bv[4];
            #pragma unroll
            for (int r = 0; r < 4; ++r) bv[r] = bias[obase + lg * 4 + r];

            if (obase < 288) {
                const int pr = (obase + lg * 4) >> 1;
                #pragma unroll
                for (int fm = 0; fm < 6; ++fm) {
                    const size_t pix = gpix + fm * 16 + l15;
                    u32 v0 = (u32)f2bf(acc[fm][0] + bv[0]) | ((u32)f2bf(acc[fm][1] + bv[1]) << 16);
                    u32 v1 = (u32)f2bf(acc[fm][2] + bv[2]) | ((u32)f2bf(acc[fm][3] + bv[3]) << 16);
                    pairT[(size_t)pr * NPIX + pix]       = v0;
                    pairT[(size_t)(pr + 1) * NPIX + pix] = v1;
                }
            } else {
                #pragma unroll
                for (int fm = 0; fm < 6; ++fm) {
                    const size_t pix = gpix + fm * 16 + l15;
                    #pragma unroll
                    for (int r = 0; r < 4; ++r) {
                        int mch = obase + lg * 4 + r - 288;
                        maskT[(size_t)mch * NPIX + pix] = f2bf(acc[fm][r] + bv[r]);
                    }
                }
            }
        }
    }
}

// ---------------------------------------------------------------------------
// Fused DCN sample+GEMM. 16-px x 3-set blocks (192 thr, 3 waves).
// One wave IS the natural 16-pixel B-fragment. Grid 2304 = 8 XCD x 288 ->
// exactly 9 blocks/CU. In-block K reduce via 8KB LDS. XCD swizzle +
// part-free accumulation proven (R5/R10).
// ---------------------------------------------------------------------------
__global__ __launch_bounds__(192) void dcn_fused(
    const u16* __restrict__ xT,     // [16][NPIX][8] bf16
    const float* __restrict__ f1,
    const float* __restrict__ f2,
    const u32*  __restrict__ pairT, // [144][NPIX] raw bf16 offset pairs
    const u16*  __restrict__ maskT, // [144][NPIX] raw bf16 mask
    const u16*  __restrict__ wdf,   // [36][4][64][8] bf16 fragment-major
    const float* __restrict__ bdcn,
    float* __restrict__ y)          // [N,64,H,W] fp32
{
    __shared__ __align__(16) v4f R[2][4][64];    // 8KB: sets 1,2 partials

    const int t    = threadIdx.x;                  // 0..191
    const int xb   = blockIdx.x;                   // 0..2303
    const int xw   = (xb & 7) * 288 + (xb >> 3);   // XCD-contiguous tile id
    const int p0   = xw * 16;
    const int ks   = t >> 6;                       // K-split set 0..2
    const int ln   = t & 63;
    const int l15  = ln & 15;
    const int lg   = ln >> 4;
    const int n    = p0 / HW;
    const int rem0 = p0 - n * HW;
    const int p    = p0 + l15;              // this thread's sampling pixel
    const int rem  = rem0 + l15;
    const int h    = rem / WW;
    const int w    = rem - h * WW;

    const char* pTc = (const char*)pairT;
    const char* mTc = (const char*)maskT;
    const char* xTc = (const char*)xT;
    const u32 p4   = (u32)p << 2;
    const u32 p2   = (u32)p << 1;
    const u32 nb16 = (u32)(n * HW) << 4;           // xT image base, 16B/pixel

    // flows + grid bases hoisted (f?yh = flow_y + h, f?xw = flow_x + w)
    const float f1yh = f1[(size_t)(n * 2 + 1) * HW + rem] + (float)h;
    const float f1xw = f1[(size_t)(n * 2 + 0) * HW + rem] + (float)w;
    const float f2yh = f2[(size_t)(n * 2 + 1) * HW + rem] + (float)h;
    const float f2xw = f2[(size_t)(n * 2 + 0) * HW + rem] + (float)w;

    auto scal = [&](int sl, u32& yx, float& mr) {
        yx = *(const u32*)(pTc + ((u32)sl * (u32)(NPIX * 4) + p4));
        mr = bf2f(*(const u16*)(mTc + ((u32)sl * (u32)(NPIX * 2) + p2)));
    };

    // coords: bilinear weights (mask folded) + issue 4 gathers
    auto coords = [&](int sl, u32 yx, float mr,
                      uint4& q00, uint4& q01, uint4& q10, uint4& q11,
                      float& w00, float& w01, float& w10, float& w11) {
        const int g  = (sl * 57) >> 9;            // sl/9 exact for sl<144
        const int kt = sl - 9 * g;
        const int ky = (kt * 11) >> 5;            // kt/3 for kt<9
        const int kx = kt - 3 * ky;
        const float fy = (g < 8) ? f1yh : f2yh;
        const float fx = (g < 8) ? f1xw : f2xw;
        const float py  = 10.0f * ftanh(lo_bf(yx)) + (fy + (float)(ky - 1));
        const float pxx = 10.0f * ftanh(hi_bf(yx)) + (fx + (float)(kx - 1));
        const float m   = fsigm(mr);

        const float y0f = floorf(py), x0f = floorf(pxx);
        const int   iy0 = (int)y0f,   ix0 = (int)x0f;
        const float wy = py - y0f, wx = pxx - x0f;
        const bool v0y = ((unsigned)iy0 < HH);
        const bool v1y = ((unsigned)(iy0 + 1) < HH);
        const bool v0x = ((unsigned)ix0 < WW);
        const bool v1x = ((unsigned)(ix0 + 1) < WW);
        const float wy0m = (1.0f - wy) * m, wy1m = wy * m;
        w00 = (v0y && v0x) ? wy0m * (1.0f - wx) : 0.0f;
        w01 = (v0y && v1x) ? wy0m * wx          : 0.0f;
        w10 = (v1y && v0x) ? wy1m * (1.0f - wx) : 0.0f;
        w11 = (v1y && v1x) ? wy1m * wx          : 0.0f;

        const int iy0c = min(max(iy0, 0), HH - 1);
        const int iy1c = min(max(iy0 + 1, 0), HH - 1);
        const int ix0c = min(max(ix0, 0), WW - 1);
        const int ix1c = min(max(ix0 + 1, 0), WW - 1);
        const u32 gof = (u32)g * (u32)(NPIX * 16) + nb16;
        const u32 r0  = gof + (u32)iy0c * (u32)(WW * 16);
        const u32 r1  = gof + (u32)iy1c * (u32)(WW * 16);
        const u32 c0  = (u32)ix0c << 4;
        const u32 c1  = (u32)ix1c << 4;
        q00 = *(const uint4*)(xTc + (r0 + c0));
        q01 = *(const uint4*)(xTc + (r0 + c1));
        q10 = *(const uint4*)(xTc + (r1 + c0));
        q11 = *(const uint4*)(xTc + (r1 + c1));
    };

    auto blend = [&](const uint4& q00, const uint4& q01,
                     const uint4& q10, const uint4& q11,
                     float w00, float w01, float w10, float w11) -> v8s {
        u32 pv0 = cvtpk(
            w00*lo_bf(q00.x) + w01*lo_bf(q01.x) + w10*lo_bf(q10.x) + w11*lo_bf(q11.x),
            w00*hi_bf(q00.x) + w01*hi_bf(q01.x) + w10*hi_bf(q10.x) + w11*hi_bf(q11.x));
        u32 pv1 = cvtpk(
            w00*lo_bf(q00.y) + w01*lo_bf(q01.y) + w10*lo_bf(q10.y) + w11*lo_bf(q11.y),
            w00*hi_bf(q00.y) + w01*hi_bf(q01.y) + w10*hi_bf(q10.y) + w11*hi_bf(q11.y));
        u32 pv2 = cvtpk(
            w00*lo_bf(q00.z) + w01*lo_bf(q01.z) + w10*lo_bf(q10.z) + w11*lo_bf(q11.z),
            w00*hi_bf(q00.z) + w01*hi_bf(q01.z) + w10*hi_bf(q10.z) + w11*hi_bf(q11.z));
        u32 pv3 = cvtpk(
            w00*lo_bf(q00.w) + w01*lo_bf(q01.w) + w10*lo_bf(q10.w) + w11*lo_bf(q11.w),
            w00*hi_bf(q00.w) + w01*hi_bf(q01.w) + w10*hi_bf(q10.w) + w11*hi_bf(q11.w));
        return u4_to_v8s(make_uint4(pv0, pv1, pv2, pv3));
    };

    v4f acc[4];
    #pragma unroll
    for (int i = 0; i < 4; ++i) acc[i] = (v4f){0.f, 0.f, 0.f, 0.f};

    const int cc0 = ks * 12;
    const int sb  = cc0 * 4 + lg;           // slot of sample i = sb + 4*i
    const char* wb = (const char*)wdf + ((u32)cc0 << 12) + ((u32)ln << 4);

    // ---- pipeline state (named, no runtime-indexed arrays) ----
    uint4 qA00, qA01, qA10, qA11;  float wA00, wA01, wA10, wA11;
    uint4 qB00, qB01, qB10, qB11;  float wB00, wB01, wB10, wB11;
    u32 yxN; float mrN;

    {   // prologue: fill A (sample 0), B (sample 1); preload scalars for 2
        u32 yx; float mr;
        scal(sb, yx, mr);
        coords(sb, yx, mr, qA00, qA01, qA10, qA11, wA00, wA01, wA10, wA11);
        scal(sb + 4, yx, mr);
        coords(sb + 4, yx, mr, qB00, qB01, qB10, qB11, wB00, wB01, wB10, wB11);
        scal(sb + 8, yxN, mrN);
    }

    #pragma unroll 1
    for (int j = 0; j < 12; j += 2) {
        {   // EVEN: consume A (sample j); refill A with sample j+2
            const char* wj = wb + ((u32)j << 12);
            v8s aW0 = *(const v8s*)(wj);
            v8s aW1 = *(const v8s*)(wj + 1024);
            v8s aW2 = *(const v8s*)(wj + 2048);
            v8s aW3 = *(const v8s*)(wj + 3072);
            v8s bP = blend(qA00, qA01, qA10, qA11, wA00, wA01, wA10, wA11);
            acc[0] = __builtin_amdgcn_mfma_f32_16x16x32_bf16(bP, aW0, acc[0], 0, 0, 0);
            acc[1] = __builtin_amdgcn_mfma_f32_16x16x32_bf16(bP, aW1, acc[1], 0, 0, 0);
            acc[2] = __builtin_amdgcn_mfma_f32_16x16x32_bf16(bP, aW2, acc[2], 0, 0, 0);
            acc[3] = __builtin_amdgcn_mfma_f32_16x16x32_bf16(bP, aW3, acc[3], 0, 0, 0);
            if (j + 2 < 12)
                coords(sb + (j + 2) * 4, yxN, mrN,
                       qA00, qA01, qA10, qA11, wA00, wA01, wA10, wA11);
            if (j + 3 < 12) scal(sb + (j + 3) * 4, yxN, mrN);
        }
        {   // ODD: consume B (sample j+1); refill B with sample j+3
            const char* wj = wb + ((u32)(j + 1) << 12);
            v8s aW0 = *(const v8s*)(wj);
            v8s aW1 = *(const v8s*)(wj + 1024);
            v8s aW2 = *(const v8s*)(wj + 2048);
            v8s aW3 = *(const v8s*)(wj + 3072);
            v8s bP = blend(qB00, qB01, qB10, qB11, wB00, wB01, wB10, wB11);
            acc[0] = __builtin_amdgcn_mfma_f32_16x16x32_bf16(bP, aW0, acc[0], 0, 0, 0);
            acc[1] = __builtin_amdgcn_mfma_f32_16x16x32_bf16(bP, aW1, acc[1], 0, 0, 0);
            acc[2] = __builtin_amdgcn_mfma_f32_16x16x32_bf16(bP, aW2, acc[2], 0, 0, 0);
            acc[3] = __builtin_amdgcn_mfma_f32_16x16x32_bf16(bP, aW3, acc[3], 0, 0, 0);
            if (j + 3 < 12)
                coords(sb + (j + 3) * 4, yxN, mrN,
                       qB00, qB01, qB10, qB11, wB00, wB01, wB10, wB11);
            if (j + 4 < 12) scal(sb + (j + 4) * 4, yxN, mrN);
        }
    }

    // ---- in-block K reduction: sets 1,2 -> LDS; set 0 sums + writes y ----
    if (ks > 0) {
        #pragma unroll
        for (int m = 0; m < 4; ++m) R[ks - 1][m][ln] = acc[m];
    }
    __syncthreads();
    if (ks == 0) {
        #pragma unroll
        for (int m = 0; m < 4; ++m) {
            v4f s = acc[m];
            v4f r1 = R[0][m][ln];
            v4f r2 = R[1][m][ln];
            const int o = m * 16 + l15;
            const float bd = bdcn[o];
            const size_t idx = (size_t)(n * C_OUT + o) * HW + rem0 + lg * 4;
            *(float4*)&y[idx] = make_float4(s[0] + r1[0] + r2[0] + bd,
                                            s[1] + r1[1] + r2[1] + bd,
                                            s[2] + r1[2] + r2[2] + bd,
                                            s[3] + r1[3] + r2[3] + bd);
        }
    }
}

// ---------------------------------------------------------------------------
extern "C" void kernel_launch(void* const* d_in, const int* in_sizes, int n_in,
                              void* d_out, int out_size, void* d_ws, size_t ws_size,
                              hipStream_t stream) {
    const float* x  = (const float*)d_in[0];
    const float* ef = (const float*)d_in[1];
    const float* f1 = (const float*)d_in[2];
    const float* f2 = (const float*)d_in[3];
    const float* w0 = (const float*)d_in[4];
    const float* b0 = (const float*)d_in[5];
    const float* w1 = (const float*)d_in[6];
    const float* b1 = (const float*)d_in[7];
    const float* w2 = (const float*)d_in[8];
    const float* b2 = (const float*)d_in[9];
    const float* w3 = (const float*)d_in[10];
    const float* b3 = (const float*)d_in[11];
    const float* wd = (const float*)d_in[12];
    const float* bd = (const float*)d_in[13];
    float* y = (float*)d_out;
    char* wsb = (char*)d_ws;

    // Workspace (bytes), 16B-aligned; total ~75.4 MB + 512B zero page.
    u16* catT  = (u16*)(wsb + 0);          // 18,874,368
    u16* h0T   = (u16*)(wsb + 18874368);   //  4,718,592
    u16* h1T   = (u16*)(wsb + 23592960);   //  4,718,592
    u16* h2T   = (u16*)(wsb + 28311552);   //  4,718,592
    u32* pairT = (u32*)(wsb + 33030144);   // 21,233,664
    u16* maskT = (u16*)(wsb + 54263808);   // 10,616,832
    u16* w0p   = (u16*)(wsb + 64880640);   //    294,912
    u16* w1p   = (u16*)(wsb + 65175552);   //     73,728
    u16* w2p   = (u16*)(wsb + 65249280);   //     73,728
    u16* w3p   = (u16*)(wsb + 65323008);   //    516,096
    u16* wdf   = (u16*)(wsb + 65839104);   //    147,456
    u16* xT    = (u16*)(wsb + 65986560);   //  9,437,184 -> ends 75,423,744
    char* zp   = (wsb + 75423744);         //        512 (zero page)

    // one fused prep dispatch: catT (2304) + xT (1152) + pack (2160) = 5616
    prep_all<<<dim3(5616), 256, 0, stream>>>(
        ef, f1, f2, x, catT, xT,
        w0, w0p, w1, w1p, w2, w2p, w3, w3p, wd, wdf, (uint4*)zp);

    conv_mfma<256, 4, 64, true,  false, 1><<<dim3(768), 256, 0, stream>>>(
        catT, w0p, b0, 64, h0T, nullptr, nullptr, zp);
    conv_mfma< 64, 1, 64, true,  false, 1><<<dim3(768), 256, 0, stream>>>(
        h0T, w1p, b1, 64, h1T, nullptr, nullptr, zp);
    conv_mfma< 64, 1, 64, true,  false, 1><<<dim3(768), 256, 0, stream>>>(
        h1T, w2p, b2, 64, h2T, nullptr, nullptr, zp);
    conv_mfma< 64, 1, 448, false, true, 7><<<dim3(NB * HH, 2), 256, 0, stream>>>(
        h2T, w3p, b3, 432, nullptr, pairT, maskT, zp);

    dcn_fused<<<dim3(NPIX / 16), 192, 0, stream>>>(
        xT, f1, f2, pairT, maskT, wdf, bd, y);
}

// Round 15
// 110.914 us; speedup vs baseline: 1.3297x; 1.0572x over previous
//
#include <hip/hip_runtime.h>
#include <math.h>

#define NB 4
#define HH 96
#define WW 96
#define HW (HH*WW)
#define NPIX (NB*HW)
#define C_IN 128
#define C_OUT 64
#define DGRP 16
#define CG 8

typedef short v8s __attribute__((ext_vector_type(8)));
typedef float v4f __attribute__((ext_vector_type(4)));
typedef unsigned short u16;
typedef unsigned int u32;

__device__ __forceinline__ u16 f2bf(float x) {
    u32 u = __float_as_uint(x);
    u32 r = (u + 0x7FFFu + ((u >> 16) & 1u)) >> 16;   // RNE
    return (u16)r;
}
__device__ __forceinline__ float bf2f(u16 h) {
    return __uint_as_float(((u32)h) << 16);
}
__device__ __forceinline__ float lo_bf(u32 w) { return __uint_as_float(w << 16); }
__device__ __forceinline__ float hi_bf(u32 w) { return __uint_as_float(w & 0xFFFF0000u); }
__device__ __forceinline__ float ftanh(float x) {
    float e = __expf(2.0f * x);
    return 1.0f - 2.0f / (e + 1.0f);
}
__device__ __forceinline__ float fsigm(float x) {
    return 1.0f / (1.0f + __expf(-x));
}
__device__ __forceinline__ v8s u4_to_v8s(uint4 q) {
    union { uint4 q; v8s s; } u; u.q = q; return u.s;
}
// HW packed fp32->bf16 RNE: dst.lo16 = bf16(a), dst.hi16 = bf16(b).
__device__ __forceinline__ u32 cvtpk(float a, float b) {
    u32 r;
    asm("v_cvt_pk_bf16_f32 %0, %1, %2" : "=v"(r) : "v"(a), "v"(b));
    return r;
}
// async global->LDS, 16B per lane (dest lane-linear, src per-lane; m104/m173)
// HAZARD (R14 lesson): dest base is wave-uniform -- NEVER call under a
// divergent predicate unless lane 0 of every active wave stays active.
typedef __attribute__((address_space(1))) const char gch1;
typedef __attribute__((address_space(3))) char ch3;
__device__ __forceinline__ void gload16(const void* g, void* l) {
    __builtin_amdgcn_global_load_lds((gch1*)g, (ch3*)l, 16, 0, 0);
}

// ---------------------------------------------------------------------------
// ONE fused prep dispatch: catT (2304 = 576x4) + xT (1152 = 576x2) +
// weight-pack (2160). Total 5616.
// ---------------------------------------------------------------------------
__device__ __forceinline__ void pack_wf_one(
    const float* __restrict__ w, u16* __restrict__ wp,
    int Cout, int CoutPad, int CIN, int CIP, int idx)
{
    const int NKF = CIP / 32, NOG = CoutPad / 16;
    int c    = idx & 7;
    int ln   = (idx >> 3) & 63;
    int rest = idx >> 9;
    int og   = rest % NOG; rest /= NOG;
    int kfg  = rest % NKF;
    int tap  = rest / NKF;
    int l15 = ln & 15, lg = ln >> 4;
    int o  = og * 16 + l15;
    int ci = kfg * 32 + lg * 8 + c;
    float v = (o < Cout && ci < CIN) ? w[((size_t)o * CIN + ci) * 9 + tap] : 0.f;
    wp[idx] = f2bf(v);
}

__global__ __launch_bounds__(256) void prep_all(
    const float* __restrict__ ef, const float* __restrict__ f1,
    const float* __restrict__ f2, const float* __restrict__ x,
    u16* __restrict__ catT, u16* __restrict__ xT,
    const float* __restrict__ w0, u16* __restrict__ w0p,
    const float* __restrict__ w1, u16* __restrict__ w1p,
    const float* __restrict__ w2, u16* __restrict__ w2p,
    const float* __restrict__ w3, u16* __restrict__ w3p,
    const float* __restrict__ wd, u16* __restrict__ wdf,
    uint4* __restrict__ zp)
{
    __shared__ float T[64][65];
    const int t = threadIdx.x;
    int bid = blockIdx.x;

    if (bid < 2304) {              // ---- catT: concat -> pixel-major bf16 ----
        const int by  = bid / 576, bx = bid - by * 576;
        const int p   = bx * 64;
        const int ch0 = by * 64;
        const int n   = p / HW;
        const int rem = p - n * HW;
        const int px  = t & 63;
        const int wv  = t >> 6;
        #pragma unroll
        for (int kk = 0; kk < 16; ++kk) {
            int chl = wv * 16 + kk;
            int ch  = ch0 + chl;
            float v = 0.f;
            if (ch < 192)      v = ef[(size_t)(n * 192 + ch) * HW + rem + px];
            else if (ch < 194) v = f1[(size_t)(n * 2 + (ch - 192)) * HW + rem + px];
            else if (ch < 196) v = f2[(size_t)(n * 2 + (ch - 194)) * HW + rem + px];
            T[chl][px] = v;
        }
        __syncthreads();
        const int s = t & 7;
        #pragma unroll
        for (int it = 0; it < 2; ++it) {
            int pxo = (t >> 3) + it * 32;
            u32 q0 = (u32)f2bf(T[s*8+0][pxo]) | ((u32)f2bf(T[s*8+1][pxo]) << 16);
            u32 q1 = (u32)f2bf(T[s*8+2][pxo]) | ((u32)f2bf(T[s*8+3][pxo]) << 16);
            u32 q2 = (u32)f2bf(T[s*8+4][pxo]) | ((u32)f2bf(T[s*8+5][pxo]) << 16);
            u32 q3 = (u32)f2bf(T[s*8+6][pxo]) | ((u32)f2bf(T[s*8+7][pxo]) << 16);
            *(uint4*)&catT[((size_t)(p + pxo)) * 256 + ch0 + s * 8] = make_uint4(q0, q1, q2, q3);
        }
        return;
    }
    bid -= 2304;
    if (bid < 1152) {              // ---- xT: x -> group-major bf16 ----
        const int by  = bid / 576, bx = bid - by * 576;
        const int p   = bx * 64;
        const int ch0 = by * 64;
        const int n   = p / HW;
        const int rem = p - n * HW;
        const int px  = t & 63;
        const int wv  = t >> 6;
        #pragma unroll
        for (int kk = 0; kk < 16; ++kk) {
            int chl = wv * 16 + kk;
            T[chl][px] = x[(size_t)(n * C_IN + ch0 + chl) * HW + rem + px];
        }
        __syncthreads();
        const int s = t & 7;
        #pragma unroll
        for (int it = 0; it < 2; ++it) {
            int pxo = (t >> 3) + it * 32;
            u32 q0 = (u32)f2bf(T[s*8+0][pxo]) | ((u32)f2bf(T[s*8+1][pxo]) << 16);
            u32 q1 = (u32)f2bf(T[s*8+2][pxo]) | ((u32)f2bf(T[s*8+3][pxo]) << 16);
            u32 q2 = (u32)f2bf(T[s*8+4][pxo]) | ((u32)f2bf(T[s*8+5][pxo]) << 16);
            u32 q3 = (u32)f2bf(T[s*8+6][pxo]) | ((u32)f2bf(T[s*8+7][pxo]) << 16);
            *(uint4*)&xT[((size_t)(ch0 / 8 + s) * NPIX + (p + pxo)) * 8] = make_uint4(q0, q1, q2, q3);
        }
        return;
    }
    bid -= 1152;                   // ---- weight pack (2160 blocks) ----
    if (bid == 0 && t < 32)
        zp[t] = make_uint4(0u, 0u, 0u, 0u);   // 512B zero page
    int idx = bid * 256 + t;
    if (idx < 147456) { pack_wf_one(w0, w0p, 64, 64, 196, 256, idx); return; }
    idx -= 147456;
    if (idx < 36864)  { pack_wf_one(w1, w1p, 64, 64, 64, 64, idx); return; }
    idx -= 36864;
    if (idx < 36864)  { pack_wf_one(w2, w2p, 64, 64, 64, 64, idx); return; }
    idx -= 36864;
    if (idx < 258048) { pack_wf_one(w3, w3p, 432, 448, 64, 64, idx); return; }
    idx -= 258048;
    {   // pack_wdf
        int c  = idx & 7;
        int ln = (idx >> 3) & 63;
        int m  = (idx >> 9) & 3;
        int kk = idx >> 11;
        int l15 = ln & 15, lg = ln >> 4;
        int o = m * 16 + l15;
        int slot = kk * 4 + lg;
        int g = slot / 9, kt = slot - 9 * g;
        wdf[idx] = f2bf(wd[((size_t)(o * C_IN + g * CG + c)) * 9 + kt]);
    }
}

// ---------------------------------------------------------------------------
// MFMA implicit-GEMM 3x3 conv, 256 thr = 4 waves. Fragment-major weights.
// XCD-aware block swizzle (T1): each XCD owns contiguous rows -> halo
// re-reads (2/3 of staging) hit the home XCD's L2, not L3.
// conv1 chunk-3 diet (R14 FIXED): ALL lanes stay active (gload_lds exec
// hazard -- R14's divergent `if(cs<4)` shifted the wave's LDS base and
// corrupted staging). Filtering is in the SOURCE address only:
// cs==0 -> catT (ch 192-199, the only live data); cs!=0 -> L2-hot zero page.
// ---------------------------------------------------------------------------
template<int CIP, int NCHUNK, int OST, bool LRELU, bool TOUT, int NOB>
__global__ __launch_bounds__(256) void conv_mfma(
    const u16* __restrict__ inT,
    const u16* __restrict__ wp,
    const float* __restrict__ bias,
    int CoutReal,
    u16* __restrict__ outT,
    u32* __restrict__ pairT,
    u16* __restrict__ maskT,
    const char* __restrict__ zpc)
{
    constexpr int COLS  = (NOB > 1) ? 100 : 50;        // padded row stride
    constexpr int LTILE = 3 * COLS * 64;               // u16 units
    constexpr int LTILE_PAD = (NOB == 1) ? LTILE + 128 : LTILE;  // +256B pad
    constexpr int LSZ   = (NCHUNK > 1) ? 2 * LTILE_PAD : LTILE_PAD;
    constexpr int NKF   = CIP / 32;
    constexpr int NOG   = OST / 16;
    __shared__ __align__(16) u16 L[LSZ];

    const int t   = threadIdx.x;
    const int tb  = blockIdx.x;
    // XCD swizzle: NOB==1 grid 768 = 8x96; NOB>1 grid 384 = 8x48 (bijective)
    const int tbs = (NOB > 1) ? ((tb & 7) * 48 + (tb >> 3))
                              : ((tb & 7) * 96 + (tb >> 3));
    const int row = (NOB > 1) ? tbs : (tbs >> 1);
    const int p0  = (NOB > 1) ? 0 : (tbs & 1) * 48;
    const int n   = row / HH;
    const int h   = row - n * HH;
    const int ln  = t & 63;
    const int wv  = t >> 6;          // 0..3
    const int l15 = ln & 15;
    const int lg  = ln >> 4;

    // ---- legacy register-staging (used by NOB>1 only) ----
    auto stage = [&](int ch, int buf) {
        const int cb = ch * 64;
        const int NCOL = (NOB > 1) ? 98 : 50;
        const int NTASK = 3 * NCOL * 8;
        u16* Lb = &L[buf * LTILE_PAD];
        #pragma unroll
        for (int it = 0; it < (NTASK + 255) / 256; ++it) {
            int task = it * 256 + t;
            if (task < NTASK) {
                int s  = task & 7;
                int cl = task >> 3;
                int r3 = cl / NCOL;
                int c  = cl - r3 * NCOL;
                int yy = h + r3 - 1;
                int xx = p0 + c - 1;
                uint4 v = make_uint4(0u, 0u, 0u, 0u);
                if ((unsigned)yy < HH && (unsigned)xx < WW)
                    v = *(const uint4*)&inT[((size_t)(n * HW + yy * WW + xx)) * CIP + cb + s * 8];
                *(uint4*)&Lb[(r3 * COLS + c) * 64 + ((s ^ (c & 7)) * 8)] = v;
            }
        }
    };

    if constexpr (NOB == 1) {
        // ---- chunk-invariant staging descriptors (1200 tasks, 5 slots) ----
        const char* inTc = (const char*)inT;
        auto mk = [&](int it, int& cs) -> const char* {
            int task = it * 256 + t;
            if (task >= 1200) { cs = 8; return zpc; }
            int s  = task & 7;
            int cl = task >> 3;
            int r3 = cl / 50;
            int c  = cl - r3 * 50;
            int yy = h + r3 - 1;
            int xx = p0 + c - 1;
            bool v = ((unsigned)yy < HH) && ((unsigned)xx < WW);
            int sp = s ^ (c & 7);               // channel-slot at position s
            cs = sp;
            u32 off = ((u32)(n * HW + yy * WW + xx) * (u32)CIP + (u32)(sp * 8)) * 2u;
            return v ? inTc + off : zpc;
        };
        int cs0, cs1, cs2, cs3, cs4;
        const char* pb0 = mk(0, cs0);
        const char* pb1 = mk(1, cs1);
        const char* pb2 = mk(2, cs2);
        const char* pb3 = mk(3, cs3);
        const char* pb4 = mk(4, cs4);

        auto gstage = [&](int ch, int buf) {
            u16* Lb = &L[buf * LTILE_PAD];
            const u32 cb2 = (u32)ch * 128u;     // chunk byte offset
            if (CIP == 256 && ch == 3) {
                // chunk 3: only slot 0 (ch 192-199) holds live data; slots
                // 1..7 are zero channels / unread (kf1 dead). ALL lanes
                // issue (exec hazard!) -- filtering via source address.
                // zpc+cb2 <= 512B page, still zeros.
                gload16(cs0 ? zpc : pb0 + cb2, &Lb[(u32)(0 * 256 + t) * 8u]);
                gload16(cs1 ? zpc : pb1 + cb2, &Lb[(u32)(1 * 256 + t) * 8u]);
                gload16(cs2 ? zpc : pb2 + cb2, &Lb[(u32)(2 * 256 + t) * 8u]);
                gload16(cs3 ? zpc : pb3 + cb2, &Lb[(u32)(3 * 256 + t) * 8u]);
                if (4 * 256 + t < 1200)      // tail: lane 0 of partial wave active
                    gload16(cs4 ? zpc : pb4 + cb2, &Lb[(u32)(4 * 256 + t) * 8u]);
            } else {
                gload16(pb0 + cb2, &Lb[(u32)(0 * 256 + t) * 8u]);
                gload16(pb1 + cb2, &Lb[(u32)(1 * 256 + t) * 8u]);
                gload16(pb2 + cb2, &Lb[(u32)(2 * 256 + t) * 8u]);
                gload16(pb3 + cb2, &Lb[(u32)(3 * 256 + t) * 8u]);
                if (4 * 256 + t < 1200)
                    gload16(pb4 + cb2, &Lb[(u32)(4 * 256 + t) * 8u]);
            }
        };

        v4f acc[3];
        #pragma unroll
        for (int i = 0; i < 3; ++i) acc[i] = (v4f){0.f, 0.f, 0.f, 0.f};

        gstage(0, 0);
        for (int ch = 0; ch < NCHUNK; ++ch) {
            __syncthreads();                 // drains gload + orders LDS
            if (ch + 1 < NCHUNK) gstage(ch + 1, (ch + 1) & 1);
            const u16* Lb = &L[(ch & 1) * LTILE_PAD];
            #pragma unroll
            for (int tap = 0; tap < 9; ++tap) {
                const int ty = tap / 3, tx = tap - ty * 3;
                #pragma unroll
                for (int kf = 0; kf < 2; ++kf) {
                    // conv1 dead block: ch3/kf1 = channels 224..255, all zero
                    if (CIP == 256 && ch == 3 && kf == 1) continue;
                    v8s b = *(const v8s*)&wp[((((size_t)tap * NKF + (ch * 2 + kf)) * NOG + wv) * 64 + ln) * 8];
                    #pragma unroll
                    for (int fm = 0; fm < 3; ++fm) {
                        int c = fm * 16 + l15 + tx;
                        v8s a = *(const v8s*)&Lb[(ty * COLS + c) * 64 + (((kf * 4 + lg) ^ (c & 7)) * 8)];
                        acc[fm] = __builtin_amdgcn_mfma_f32_16x16x32_bf16(a, b, acc[fm], 0, 0, 0);
                    }
                }
            }
        }

        int o = wv * 16 + l15;
        float bv = (o < CoutReal) ? bias[o] : 0.f;
        #pragma unroll
        for (int fm = 0; fm < 3; ++fm) {
            #pragma unroll
            for (int r = 0; r < 4; ++r) {
                int px = p0 + fm * 16 + lg * 4 + r;
                float v = acc[fm][r] + bv;
                if (LRELU) v = (v >= 0.f) ? v : 0.1f * v;
                outT[((size_t)(n * HW + h * WW + px)) * OST + o] = f2bf(v);
            }
        }
    } else {
        stage(0, 0);
        __syncthreads();
        const size_t gpix = (size_t)n * HW + h * WW;
        const int ob_lo = blockIdx.y * 4;
        const int ob_hi = (ob_lo + 4 < NOB) ? ob_lo + 4 : NOB;

        for (int ob = ob_lo; ob < ob_hi; ++ob) {
            const int obase = ob * 64 + wv * 16;
            if (obase >= 432) continue;

            v4f acc[6];
            #pragma unroll
            for (int i = 0; i < 6; ++i) acc[i] = (v4f){0.f, 0.f, 0.f, 0.f};

            #pragma unroll
            for (int tap = 0; tap < 9; ++tap) {
                const int ty = tap / 3, tx = tap - ty * 3;
                #pragma unroll
                for (int kf = 0; kf < 2; ++kf) {
                    v8s bw = *(const v8s*)&wp[((((size_t)tap * NKF + kf) * NOG + (ob * 4 + wv)) * 64 + ln) * 8];
                    #pragma unroll
                    for (int fm = 0; fm < 6; ++fm) {
                        int c = fm * 16 + l15 + tx;
                        v8s a = *(const v8s*)&L[(ty * COLS + c) * 64 + (((kf * 4 + lg) ^ (c & 7)) * 8)];
                        acc[fm] = __builtin_amdgcn_mfma_f32_16x16x32_bf16(bw, a, acc[fm], 0, 0, 0);
                    }
                }
            }

            float bv[4];
            #pragma unroll
            for (int r = 0; r < 4; ++r) bv[r] = bias[obase + lg * 4 + r];

            if (obase < 288) {
                const int pr = (obase + lg * 4) >> 1;
                #pragma unroll
                for (int fm = 0; fm < 6; ++fm) {
                    const size_t pix = gpix + fm * 16 + l15;
                    u32 v0 = (u32)f2bf(acc[fm][0] + bv[0]) | ((u32)f2bf(acc[fm][1] + bv[1]) << 16);
                    u32 v1 = (u32)f2bf(acc[fm][2] + bv[2]) | ((u32)f2bf(acc[fm][3] + bv[3]) << 16);
                    pairT[(size_t)pr * NPIX + pix]       = v0;
                    pairT[(size_t)(pr + 1) * NPIX + pix] = v1;
                }
            } else {
                #pragma unroll
                for (int fm = 0; fm < 6; ++fm) {
                    const size_t pix = gpix + fm * 16 + l15;
                    #pragma unroll
                    for (int r = 0; r < 4; ++r) {
                        int mch = obase + lg * 4 + r - 288;
                        maskT[(size_t)mch * NPIX + pix] = f2bf(acc[fm][r] + bv[r]);
                    }
                }
            }
        }
    }
}

// ---------------------------------------------------------------------------
// Fused DCN sample+GEMM. 16-px x 3-set blocks (192 thr, 3 waves), grid
// 2304 = 8 XCD x 288 -> 9 blocks/CU even. In-block K reduce via 8KB LDS.
// (R13: 47.5us, VALU 57%, FETCH 21.7MB -- proven config, unchanged.)
// ---------------------------------------------------------------------------
__global__ __launch_bounds__(192) void dcn_fused(
    const u16* __restrict__ xT,     // [16][NPIX][8] bf16
    const float* __restrict__ f1,
    const float* __restrict__ f2,
    const u32*  __restrict__ pairT, // [144][NPIX] raw bf16 offset pairs
    const u16*  __restrict__ maskT, // [144][NPIX] raw bf16 mask
    const u16*  __restrict__ wdf,   // [36][4][64][8] bf16 fragment-major
    const float* __restrict__ bdcn,
    float* __restrict__ y)          // [N,64,H,W] fp32
{
    __shared__ __align__(16) v4f R[2][4][64];    // 8KB: sets 1,2 partials

    const int t    = threadIdx.x;                  // 0..191
    const int xb   = blockIdx.x;                   // 0..2303
    const int xw   = (xb & 7) * 288 + (xb >> 3);   // XCD-contiguous tile id
    const int p0   = xw * 16;
    const int ks   = t >> 6;                       // K-split set 0..2
    const int ln   = t & 63;
    const int l15  = ln & 15;
    const int lg   = ln >> 4;
    const int n    = p0 / HW;
    const int rem0 = p0 - n * HW;
    const int p    = p0 + l15;              // this thread's sampling pixel
    const int rem  = rem0 + l15;
    const int h    = rem / WW;
    const int w    = rem - h * WW;

    const char* pTc = (const char*)pairT;
    const char* mTc = (const char*)maskT;
    const char* xTc = (const char*)xT;
    const u32 p4   = (u32)p << 2;
    const u32 p2   = (u32)p << 1;
    const u32 nb16 = (u32)(n * HW) << 4;           // xT image base, 16B/pixel

    // flows + grid bases hoisted (f?yh = flow_y + h, f?xw = flow_x + w)
    const float f1yh = f1[(size_t)(n * 2 + 1) * HW + rem] + (float)h;
    const float f1xw = f1[(size_t)(n * 2 + 0) * HW + rem] + (float)w;
    const float f2yh = f2[(size_t)(n * 2 + 1) * HW + rem] + (float)h;
    const float f2xw = f2[(size_t)(n * 2 + 0) * HW + rem] + (float)w;

    auto scal = [&](int sl, u32& yx, float& mr) {
        yx = *(const u32*)(pTc + ((u32)sl * (u32)(NPIX * 4) + p4));
        mr = bf2f(*(const u16*)(mTc + ((u32)sl * (u32)(NPIX * 2) + p2)));
    };

    // coords: bilinear weights (mask folded) + issue 4 gathers
    auto coords = [&](int sl, u32 yx, float mr,
                      uint4& q00, uint4& q01, uint4& q10, uint4& q11,
                      float& w00, float& w01, float& w10, float& w11) {
        const int g  = (sl * 57) >> 9;            // sl/9 exact for sl<144
        const int kt = sl - 9 * g;
        const int ky = (kt * 11) >> 5;            // kt/3 for kt<9
        const int kx = kt - 3 * ky;
        const float fy = (g < 8) ? f1yh : f2yh;
        const float fx = (g < 8) ? f1xw : f2xw;
        const float py  = 10.0f * ftanh(lo_bf(yx)) + (fy + (float)(ky - 1));
        const float pxx = 10.0f * ftanh(hi_bf(yx)) + (fx + (float)(kx - 1));
        const float m   = fsigm(mr);

        const float y0f = floorf(py), x0f = floorf(pxx);
        const int   iy0 = (int)y0f,   ix0 = (int)x0f;
        const float wy = py - y0f, wx = pxx - x0f;
        const bool v0y = ((unsigned)iy0 < HH);
        const bool v1y = ((unsigned)(iy0 + 1) < HH);
        const bool v0x = ((unsigned)ix0 < WW);
        const bool v1x = ((unsigned)(ix0 + 1) < WW);
        const float wy0m = (1.0f - wy) * m, wy1m = wy * m;
        w00 = (v0y && v0x) ? wy0m * (1.0f - wx) : 0.0f;
        w01 = (v0y && v1x) ? wy0m * wx          : 0.0f;
        w10 = (v1y && v0x) ? wy1m * (1.0f - wx) : 0.0f;
        w11 = (v1y && v1x) ? wy1m * wx          : 0.0f;

        const int iy0c = min(max(iy0, 0), HH - 1);
        const int iy1c = min(max(iy0 + 1, 0), HH - 1);
        const int ix0c = min(max(ix0, 0), WW - 1);
        const int ix1c = min(max(ix0 + 1, 0), WW - 1);
        const u32 gof = (u32)g * (u32)(NPIX * 16) + nb16;
        const u32 r0  = gof + (u32)iy0c * (u32)(WW * 16);
        const u32 r1  = gof + (u32)iy1c * (u32)(WW * 16);
        const u32 c0  = (u32)ix0c << 4;
        const u32 c1  = (u32)ix1c << 4;
        q00 = *(const uint4*)(xTc + (r0 + c0));
        q01 = *(const uint4*)(xTc + (r0 + c1));
        q10 = *(const uint4*)(xTc + (r1 + c0));
        q11 = *(const uint4*)(xTc + (r1 + c1));
    };

    auto blend = [&](const uint4& q00, const uint4& q01,
                     const uint4& q10, const uint4& q11,
                     float w00, float w01, float w10, float w11) -> v8s {
        u32 pv0 = cvtpk(
            w00*lo_bf(q00.x) + w01*lo_bf(q01.x) + w10*lo_bf(q10.x) + w11*lo_bf(q11.x),
            w00*hi_bf(q00.x) + w01*hi_bf(q01.x) + w10*hi_bf(q10.x) + w11*hi_bf(q11.x));
        u32 pv1 = cvtpk(
            w00*lo_bf(q00.y) + w01*lo_bf(q01.y) + w10*lo_bf(q10.y) + w11*lo_bf(q11.y),
            w00*hi_bf(q00.y) + w01*hi_bf(q01.y) + w10*hi_bf(q10.y) + w11*hi_bf(q11.y));
        u32 pv2 = cvtpk(
            w00*lo_bf(q00.z) + w01*lo_bf(q01.z) + w10*lo_bf(q10.z) + w11*lo_bf(q11.z),
            w00*hi_bf(q00.z) + w01*hi_bf(q01.z) + w10*hi_bf(q10.z) + w11*hi_bf(q11.z));
        u32 pv3 = cvtpk(
            w00*lo_bf(q00.w) + w01*lo_bf(q01.w) + w10*lo_bf(q10.w) + w11*lo_bf(q11.w),
            w00*hi_bf(q00.w) + w01*hi_bf(q01.w) + w10*hi_bf(q10.w) + w11*hi_bf(q11.w));
        return u4_to_v8s(make_uint4(pv0, pv1, pv2, pv3));
    };

    v4f acc[4];
    #pragma unroll
    for (int i = 0; i < 4; ++i) acc[i] = (v4f){0.f, 0.f, 0.f, 0.f};

    const int cc0 = ks * 12;
    const int sb  = cc0 * 4 + lg;           // slot of sample i = sb + 4*i
    const char* wb = (const char*)wdf + ((u32)cc0 << 12) + ((u32)ln << 4);

    // ---- pipeline state (named, no runtime-indexed arrays) ----
    uint4 qA00, qA01, qA10, qA11;  float wA00, wA01, wA10, wA11;
    uint4 qB00, qB01, qB10, qB11;  float wB00, wB01, wB10, wB11;
    u32 yxN; float mrN;

    {   // prologue: fill A (sample 0), B (sample 1); preload scalars for 2
        u32 yx; float mr;
        scal(sb, yx, mr);
        coords(sb, yx, mr, qA00, qA01, qA10, qA11, wA00, wA01, wA10, wA11);
        scal(sb + 4, yx, mr);
        coords(sb + 4, yx, mr, qB00, qB01, qB10, qB11, wB00, wB01, wB10, wB11);
        scal(sb + 8, yxN, mrN);
    }

    #pragma unroll 1
    for (int j = 0; j < 12; j += 2) {
        {   // EVEN: consume A (sample j); refill A with sample j+2
            const char* wj = wb + ((u32)j << 12);
            v8s aW0 = *(const v8s*)(wj);
            v8s aW1 = *(const v8s*)(wj + 1024);
            v8s aW2 = *(const v8s*)(wj + 2048);
            v8s aW3 = *(const v8s*)(wj + 3072);
            v8s bP = blend(qA00, qA01, qA10, qA11, wA00, wA01, wA10, wA11);
            acc[0] = __builtin_amdgcn_mfma_f32_16x16x32_bf16(bP, aW0, acc[0], 0, 0, 0);
            acc[1] = __builtin_amdgcn_mfma_f32_16x16x32_bf16(bP, aW1, acc[1], 0, 0, 0);
            acc[2] = __builtin_amdgcn_mfma_f32_16x16x32_bf16(bP, aW2, acc[2], 0, 0, 0);
            acc[3] = __builtin_amdgcn_mfma_f32_16x16x32_bf16(bP, aW3, acc[3], 0, 0, 0);
            if (j + 2 < 12)
                coords(sb + (j + 2) * 4, yxN, mrN,
                       qA00, qA01, qA10, qA11, wA00, wA01, wA10, wA11);
            if (j + 3 < 12) scal(sb + (j + 3) * 4, yxN, mrN);
        }
        {   // ODD: consume B (sample j+1); refill B with sample j+3
            const char* wj = wb + ((u32)(j + 1) << 12);
            v8s aW0 = *(const v8s*)(wj);
            v8s aW1 = *(const v8s*)(wj + 1024);
            v8s aW2 = *(const v8s*)(wj + 2048);
            v8s aW3 = *(const v8s*)(wj + 3072);
            v8s bP = blend(qB00, qB01, qB10, qB11, wB00, wB01, wB10, wB11);
            acc[0] = __builtin_amdgcn_mfma_f32_16x16x32_bf16(bP, aW0, acc[0], 0, 0, 0);
            acc[1] = __builtin_amdgcn_mfma_f32_16x16x32_bf16(bP, aW1, acc[1], 0, 0, 0);
            acc[2] = __builtin_amdgcn_mfma_f32_16x16x32_bf16(bP, aW2, acc[2], 0, 0, 0);
            acc[3] = __builtin_amdgcn_mfma_f32_16x16x32_bf16(bP, aW3, acc[3], 0, 0, 0);
            if (j + 3 < 12)
                coords(sb + (j + 3) * 4, yxN, mrN,
                       qB00, qB01, qB10, qB11, wB00, wB01, wB10, wB11);
            if (j + 4 < 12) scal(sb + (j + 4) * 4, yxN, mrN);
        }
    }

    // ---- in-block K reduction: sets 1,2 -> LDS; set 0 sums + writes y ----
    if (ks > 0) {
        #pragma unroll
        for (int m = 0; m < 4; ++m) R[ks - 1][m][ln] = acc[m];
    }
    __syncthreads();
    if (ks == 0) {
        #pragma unroll
        for (int m = 0; m < 4; ++m) {
            v4f s = acc[m];
            v4f r1 = R[0][m][ln];
            v4f r2 = R[1][m][ln];
            const int o = m * 16 + l15;
            const float bd = bdcn[o];
            const size_t idx = (size_t)(n * C_OUT + o) * HW + rem0 + lg * 4;
            *(float4*)&y[idx] = make_float4(s[0] + r1[0] + r2[0] + bd,
                                            s[1] + r1[1] + r2[1] + bd,
                                            s[2] + r1[2] + r2[2] + bd,
                                            s[3] + r1[3] + r2[3] + bd);
        }
    }
}

// ---------------------------------------------------------------------------
extern "C" void kernel_launch(void* const* d_in, const int* in_sizes, int n_in,
                              void* d_out, int out_size, void* d_ws, size_t ws_size,
                              hipStream_t stream) {
    const float* x  = (const float*)d_in[0];
    const float* ef = (const float*)d_in[1];
    const float* f1 = (const float*)d_in[2];
    const float* f2 = (const float*)d_in[3];
    const float* w0 = (const float*)d_in[4];
    const float* b0 = (const float*)d_in[5];
    const float* w1 = (const float*)d_in[6];
    const float* b1 = (const float*)d_in[7];
    const float* w2 = (const float*)d_in[8];
    const float* b2 = (const float*)d_in[9];
    const float* w3 = (const float*)d_in[10];
    const float* b3 = (const float*)d_in[11];
    const float* wd = (const float*)d_in[12];
    const float* bd = (const float*)d_in[13];
    float* y = (float*)d_out;
    char* wsb = (char*)d_ws;

    // Workspace (bytes), 16B-aligned; total ~75.4 MB + 512B zero page.
    u16* catT  = (u16*)(wsb + 0);          // 18,874,368
    u16* h0T   = (u16*)(wsb + 18874368);   //  4,718,592
    u16* h1T   = (u16*)(wsb + 23592960);   //  4,718,592
    u16* h2T   = (u16*)(wsb + 28311552);   //  4,718,592
    u32* pairT = (u32*)(wsb + 33030144);   // 21,233,664
    u16* maskT = (u16*)(wsb + 54263808);   // 10,616,832
    u16* w0p   = (u16*)(wsb + 64880640);   //    294,912
    u16* w1p   = (u16*)(wsb + 65175552);   //     73,728
    u16* w2p   = (u16*)(wsb + 65249280);   //     73,728
    u16* w3p   = (u16*)(wsb + 65323008);   //    516,096
    u16* wdf   = (u16*)(wsb + 65839104);   //    147,456
    u16* xT    = (u16*)(wsb + 65986560);   //  9,437,184 -> ends 75,423,744
    char* zp   = (wsb + 75423744);         //        512 (zero page)

    // one fused prep dispatch: catT (2304) + xT (1152) + pack (2160) = 5616
    prep_all<<<dim3(5616), 256, 0, stream>>>(
        ef, f1, f2, x, catT, xT,
        w0, w0p, w1, w1p, w2, w2p, w3, w3p, wd, wdf, (uint4*)zp);

    conv_mfma<256, 4, 64, true,  false, 1><<<dim3(768), 256, 0, stream>>>(
        catT, w0p, b0, 64, h0T, nullptr, nullptr, zp);
    conv_mfma< 64, 1, 64, true,  false, 1><<<dim3(768), 256, 0, stream>>>(
        h0T, w1p, b1, 64, h1T, nullptr, nullptr, zp);
    conv_mfma< 64, 1, 64, true,  false, 1><<<dim3(768), 256, 0, stream>>>(
        h1T, w2p, b2, 64, h2T, nullptr, nullptr, zp);
    conv_mfma< 64, 1, 448, false, true, 7><<<dim3(NB * HH, 2), 256, 0, stream>>>(
        h2T, w3p, b3, 432, nullptr, pairT, maskT, zp);

    dcn_fused<<<dim3(NPIX / 16), 192, 0, stream>>>(
        xT, f1, f2, pairT, maskT, wdf, bd, y);
}

// Round 16
// 110.066 us; speedup vs baseline: 1.3400x; 1.0077x over previous
//
#include <hip/hip_runtime.h>
#include <math.h>

#define NB 4
#define HH 96
#define WW 96
#define HW (HH*WW)
#define NPIX (NB*HW)
#define C_IN 128
#define C_OUT 64
#define DGRP 16
#define CG 8

typedef short v8s __attribute__((ext_vector_type(8)));
typedef float v4f __attribute__((ext_vector_type(4)));
typedef unsigned short u16;
typedef unsigned int u32;

__device__ __forceinline__ u16 f2bf(float x) {
    u32 u = __float_as_uint(x);
    u32 r = (u + 0x7FFFu + ((u >> 16) & 1u)) >> 16;   // RNE
    return (u16)r;
}
__device__ __forceinline__ float bf2f(u16 h) {
    return __uint_as_float(((u32)h) << 16);
}
__device__ __forceinline__ float lo_bf(u32 w) { return __uint_as_float(w << 16); }
__device__ __forceinline__ float hi_bf(u32 w) { return __uint_as_float(w & 0xFFFF0000u); }
__device__ __forceinline__ float ftanh(float x) {
    float e = __expf(2.0f * x);
    return 1.0f - 2.0f / (e + 1.0f);
}
__device__ __forceinline__ float fsigm(float x) {
    return 1.0f / (1.0f + __expf(-x));
}
__device__ __forceinline__ v8s u4_to_v8s(uint4 q) {
    union { uint4 q; v8s s; } u; u.q = q; return u.s;
}
// HW packed fp32->bf16 RNE: dst.lo16 = bf16(a), dst.hi16 = bf16(b).
__device__ __forceinline__ u32 cvtpk(float a, float b) {
    u32 r;
    asm("v_cvt_pk_bf16_f32 %0, %1, %2" : "=v"(r) : "v"(a), "v"(b));
    return r;
}
// async global->LDS, 16B per lane (dest lane-linear, src per-lane; m104/m173)
// HAZARD (R14 lesson): dest base is wave-uniform -- NEVER call under a
// divergent predicate unless lane 0 of every active wave stays active.
typedef __attribute__((address_space(1))) const char gch1;
typedef __attribute__((address_space(3))) char ch3;
__device__ __forceinline__ void gload16(const void* g, void* l) {
    __builtin_amdgcn_global_load_lds((gch1*)g, (ch3*)l, 16, 0, 0);
}

// ---------------------------------------------------------------------------
// ONE fused prep dispatch: catT (2304 = 576x4) + xT (1152 = 576x2) +
// weight-pack (2160). Total 5616.
// ---------------------------------------------------------------------------
__device__ __forceinline__ void pack_wf_one(
    const float* __restrict__ w, u16* __restrict__ wp,
    int Cout, int CoutPad, int CIN, int CIP, int idx)
{
    const int NKF = CIP / 32, NOG = CoutPad / 16;
    int c    = idx & 7;
    int ln   = (idx >> 3) & 63;
    int rest = idx >> 9;
    int og   = rest % NOG; rest /= NOG;
    int kfg  = rest % NKF;
    int tap  = rest / NKF;
    int l15 = ln & 15, lg = ln >> 4;
    int o  = og * 16 + l15;
    int ci = kfg * 32 + lg * 8 + c;
    float v = (o < Cout && ci < CIN) ? w[((size_t)o * CIN + ci) * 9 + tap] : 0.f;
    wp[idx] = f2bf(v);
}

__global__ __launch_bounds__(256) void prep_all(
    const float* __restrict__ ef, const float* __restrict__ f1,
    const float* __restrict__ f2, const float* __restrict__ x,
    u16* __restrict__ catT, u16* __restrict__ xT,
    const float* __restrict__ w0, u16* __restrict__ w0p,
    const float* __restrict__ w1, u16* __restrict__ w1p,
    const float* __restrict__ w2, u16* __restrict__ w2p,
    const float* __restrict__ w3, u16* __restrict__ w3p,
    const float* __restrict__ wd, u16* __restrict__ wdf,
    uint4* __restrict__ zp)
{
    __shared__ float T[64][65];
    const int t = threadIdx.x;
    int bid = blockIdx.x;

    if (bid < 2304) {              // ---- catT: concat -> pixel-major bf16 ----
        const int by  = bid / 576, bx = bid - by * 576;
        const int p   = bx * 64;
        const int ch0 = by * 64;
        const int n   = p / HW;
        const int rem = p - n * HW;
        const int px  = t & 63;
        const int wv  = t >> 6;
        #pragma unroll
        for (int kk = 0; kk < 16; ++kk) {
            int chl = wv * 16 + kk;
            int ch  = ch0 + chl;
            float v = 0.f;
            if (ch < 192)      v = ef[(size_t)(n * 192 + ch) * HW + rem + px];
            else if (ch < 194) v = f1[(size_t)(n * 2 + (ch - 192)) * HW + rem + px];
            else if (ch < 196) v = f2[(size_t)(n * 2 + (ch - 194)) * HW + rem + px];
            T[chl][px] = v;
        }
        __syncthreads();
        const int s = t & 7;
        #pragma unroll
        for (int it = 0; it < 2; ++it) {
            int pxo = (t >> 3) + it * 32;
            u32 q0 = (u32)f2bf(T[s*8+0][pxo]) | ((u32)f2bf(T[s*8+1][pxo]) << 16);
            u32 q1 = (u32)f2bf(T[s*8+2][pxo]) | ((u32)f2bf(T[s*8+3][pxo]) << 16);
            u32 q2 = (u32)f2bf(T[s*8+4][pxo]) | ((u32)f2bf(T[s*8+5][pxo]) << 16);
            u32 q3 = (u32)f2bf(T[s*8+6][pxo]) | ((u32)f2bf(T[s*8+7][pxo]) << 16);
            *(uint4*)&catT[((size_t)(p + pxo)) * 256 + ch0 + s * 8] = make_uint4(q0, q1, q2, q3);
        }
        return;
    }
    bid -= 2304;
    if (bid < 1152) {              // ---- xT: x -> group-major bf16 ----
        const int by  = bid / 576, bx = bid - by * 576;
        const int p   = bx * 64;
        const int ch0 = by * 64;
        const int n   = p / HW;
        const int rem = p - n * HW;
        const int px  = t & 63;
        const int wv  = t >> 6;
        #pragma unroll
        for (int kk = 0; kk < 16; ++kk) {
            int chl = wv * 16 + kk;
            T[chl][px] = x[(size_t)(n * C_IN + ch0 + chl) * HW + rem + px];
        }
        __syncthreads();
        const int s = t & 7;
        #pragma unroll
        for (int it = 0; it < 2; ++it) {
            int pxo = (t >> 3) + it * 32;
            u32 q0 = (u32)f2bf(T[s*8+0][pxo]) | ((u32)f2bf(T[s*8+1][pxo]) << 16);
            u32 q1 = (u32)f2bf(T[s*8+2][pxo]) | ((u32)f2bf(T[s*8+3][pxo]) << 16);
            u32 q2 = (u32)f2bf(T[s*8+4][pxo]) | ((u32)f2bf(T[s*8+5][pxo]) << 16);
            u32 q3 = (u32)f2bf(T[s*8+6][pxo]) | ((u32)f2bf(T[s*8+7][pxo]) << 16);
            *(uint4*)&xT[((size_t)(ch0 / 8 + s) * NPIX + (p + pxo)) * 8] = make_uint4(q0, q1, q2, q3);
        }
        return;
    }
    bid -= 1152;                   // ---- weight pack (2160 blocks) ----
    if (bid == 0 && t < 32)
        zp[t] = make_uint4(0u, 0u, 0u, 0u);   // 512B zero page
    int idx = bid * 256 + t;
    if (idx < 147456) { pack_wf_one(w0, w0p, 64, 64, 196, 256, idx); return; }
    idx -= 147456;
    if (idx < 36864)  { pack_wf_one(w1, w1p, 64, 64, 64, 64, idx); return; }
    idx -= 36864;
    if (idx < 36864)  { pack_wf_one(w2, w2p, 64, 64, 64, 64, idx); return; }
    idx -= 36864;
    if (idx < 258048) { pack_wf_one(w3, w3p, 432, 448, 64, 64, idx); return; }
    idx -= 258048;
    {   // pack_wdf
        int c  = idx & 7;
        int ln = (idx >> 3) & 63;
        int m  = (idx >> 9) & 3;
        int kk = idx >> 11;
        int l15 = ln & 15, lg = ln >> 4;
        int o = m * 16 + l15;
        int slot = kk * 4 + lg;
        int g = slot / 9, kt = slot - 9 * g;
        wdf[idx] = f2bf(wd[((size_t)(o * C_IN + g * CG + c)) * 9 + kt]);
    }
}

// ---------------------------------------------------------------------------
// MFMA implicit-GEMM 3x3 conv, 256 thr = 4 waves. Fragment-major weights.
// XCD-aware block swizzle (T1): each XCD owns contiguous rows -> halo
// re-reads hit the home XCD's L2, not L3 (R15: -6.4us proven).
// R16: conv3 (NOB>1) staging converted to global_load_lds too. With
// COLS=98 (compute reads c<=97) the LDS dest is EXACTLY task*16B --
// lane-linear -- and the bank swizzle moves to the source address
// (sp = s^(c&7), m173). OOB -> zero page via SOURCE selection with all
// lanes active (R14 exec-hazard lesson); it=9 tail has lane 0 active.
// ---------------------------------------------------------------------------
template<int CIP, int NCHUNK, int OST, bool LRELU, bool TOUT, int NOB>
__global__ __launch_bounds__(256) void conv_mfma(
    const u16* __restrict__ inT,
    const u16* __restrict__ wp,
    const float* __restrict__ bias,
    int CoutReal,
    u16* __restrict__ outT,
    u32* __restrict__ pairT,
    u16* __restrict__ maskT,
    const char* __restrict__ zpc)
{
    constexpr int COLS  = (NOB > 1) ? 98 : 50;         // row stride (R16: 98)
    constexpr int LTILE = 3 * COLS * 64;               // u16 units
    constexpr int LTILE_PAD = (NOB == 1) ? LTILE + 128 : LTILE;  // +256B pad
    constexpr int LSZ   = (NCHUNK > 1) ? 2 * LTILE_PAD : LTILE_PAD;
    constexpr int NKF   = CIP / 32;
    constexpr int NOG   = OST / 16;
    __shared__ __align__(16) u16 L[LSZ];

    const int t   = threadIdx.x;
    const int tb  = blockIdx.x;
    // XCD swizzle: NOB==1 grid 768 = 8x96; NOB>1 grid 384 = 8x48 (bijective)
    const int tbs = (NOB > 1) ? ((tb & 7) * 48 + (tb >> 3))
                              : ((tb & 7) * 96 + (tb >> 3));
    const int row = (NOB > 1) ? tbs : (tbs >> 1);
    const int p0  = (NOB > 1) ? 0 : (tbs & 1) * 48;
    const int n   = row / HH;
    const int h   = row - n * HH;
    const int ln  = t & 63;
    const int wv  = t >> 6;          // 0..3
    const int l15 = ln & 15;
    const int lg  = ln >> 4;

    if constexpr (NOB == 1) {
        // ---- chunk-invariant staging descriptors (1200 tasks, 5 slots) ----
        const char* inTc = (const char*)inT;
        auto mk = [&](int it, int& cs) -> const char* {
            int task = it * 256 + t;
            if (task >= 1200) { cs = 8; return zpc; }
            int s  = task & 7;
            int cl = task >> 3;
            int r3 = cl / 50;
            int c  = cl - r3 * 50;
            int yy = h + r3 - 1;
            int xx = p0 + c - 1;
            bool v = ((unsigned)yy < HH) && ((unsigned)xx < WW);
            int sp = s ^ (c & 7);               // channel-slot at position s
            cs = sp;
            u32 off = ((u32)(n * HW + yy * WW + xx) * (u32)CIP + (u32)(sp * 8)) * 2u;
            return v ? inTc + off : zpc;
        };
        int cs0, cs1, cs2, cs3, cs4;
        const char* pb0 = mk(0, cs0);
        const char* pb1 = mk(1, cs1);
        const char* pb2 = mk(2, cs2);
        const char* pb3 = mk(3, cs3);
        const char* pb4 = mk(4, cs4);

        auto gstage = [&](int ch, int buf) {
            u16* Lb = &L[buf * LTILE_PAD];
            const u32 cb2 = (u32)ch * 128u;     // chunk byte offset
            if (CIP == 256 && ch == 3) {
                // chunk 3: only slot 0 (ch 192-199) live; all lanes issue,
                // filtering in the SOURCE address (exec hazard).
                gload16(cs0 ? zpc : pb0 + cb2, &Lb[(u32)(0 * 256 + t) * 8u]);
                gload16(cs1 ? zpc : pb1 + cb2, &Lb[(u32)(1 * 256 + t) * 8u]);
                gload16(cs2 ? zpc : pb2 + cb2, &Lb[(u32)(2 * 256 + t) * 8u]);
                gload16(cs3 ? zpc : pb3 + cb2, &Lb[(u32)(3 * 256 + t) * 8u]);
                if (4 * 256 + t < 1200)      // tail: lane 0 active
                    gload16(cs4 ? zpc : pb4 + cb2, &Lb[(u32)(4 * 256 + t) * 8u]);
            } else {
                gload16(pb0 + cb2, &Lb[(u32)(0 * 256 + t) * 8u]);
                gload16(pb1 + cb2, &Lb[(u32)(1 * 256 + t) * 8u]);
                gload16(pb2 + cb2, &Lb[(u32)(2 * 256 + t) * 8u]);
                gload16(pb3 + cb2, &Lb[(u32)(3 * 256 + t) * 8u]);
                if (4 * 256 + t < 1200)
                    gload16(pb4 + cb2, &Lb[(u32)(4 * 256 + t) * 8u]);
            }
        };

        v4f acc[3];
        #pragma unroll
        for (int i = 0; i < 3; ++i) acc[i] = (v4f){0.f, 0.f, 0.f, 0.f};

        gstage(0, 0);
        for (int ch = 0; ch < NCHUNK; ++ch) {
            __syncthreads();                 // drains gload + orders LDS
            if (ch + 1 < NCHUNK) gstage(ch + 1, (ch + 1) & 1);
            const u16* Lb = &L[(ch & 1) * LTILE_PAD];
            #pragma unroll
            for (int tap = 0; tap < 9; ++tap) {
                const int ty = tap / 3, tx = tap - ty * 3;
                #pragma unroll
                for (int kf = 0; kf < 2; ++kf) {
                    // conv1 dead block: ch3/kf1 = channels 224..255, all zero
                    if (CIP == 256 && ch == 3 && kf == 1) continue;
                    v8s b = *(const v8s*)&wp[((((size_t)tap * NKF + (ch * 2 + kf)) * NOG + wv) * 64 + ln) * 8];
                    #pragma unroll
                    for (int fm = 0; fm < 3; ++fm) {
                        int c = fm * 16 + l15 + tx;
                        v8s a = *(const v8s*)&Lb[(ty * COLS + c) * 64 + (((kf * 4 + lg) ^ (c & 7)) * 8)];
                        acc[fm] = __builtin_amdgcn_mfma_f32_16x16x32_bf16(a, b, acc[fm], 0, 0, 0);
                    }
                }
            }
        }

        int o = wv * 16 + l15;
        float bv = (o < CoutReal) ? bias[o] : 0.f;
        #pragma unroll
        for (int fm = 0; fm < 3; ++fm) {
            #pragma unroll
            for (int r = 0; r < 4; ++r) {
                int px = p0 + fm * 16 + lg * 4 + r;
                float v = acc[fm][r] + bv;
                if (LRELU) v = (v >= 0.f) ? v : 0.1f * v;
                outT[((size_t)(n * HW + h * WW + px)) * OST + o] = f2bf(v);
            }
        }
    } else {
        // ---- conv3: gload_lds staging, dest = task*16B (COLS==NCOL==98) --
        const char* inTc = (const char*)inT;
        {
            #pragma unroll
            for (int it = 0; it < 9; ++it) {
                int task = it * 256 + t;            // 0..2303
                int s  = task & 7;
                int cl = task >> 3;
                int r3 = cl / 98;
                int c  = cl - r3 * 98;
                int yy = h + r3 - 1;
                int xx = c - 1;                     // p0 == 0
                bool v = ((unsigned)yy < HH) && ((unsigned)xx < WW);
                int sp = s ^ (c & 7);               // source-side bank swizzle
                u32 off = ((u32)(n * HW + yy * WW + xx) * (u32)CIP + (u32)(sp * 8)) * 2u;
                gload16(v ? inTc + off : zpc, &L[(u32)task * 8u]);
            }
            if (t < 48) {                           // tail 2304..2351, lane0 ok
                int task = 9 * 256 + t;
                int s  = task & 7;
                int cl = task >> 3;
                int r3 = cl / 98;
                int c  = cl - r3 * 98;
                int yy = h + r3 - 1;
                int xx = c - 1;
                bool v = ((unsigned)yy < HH) && ((unsigned)xx < WW);
                int sp = s ^ (c & 7);
                u32 off = ((u32)(n * HW + yy * WW + xx) * (u32)CIP + (u32)(sp * 8)) * 2u;
                gload16(v ? inTc + off : zpc, &L[(u32)task * 8u]);
            }
        }
        __syncthreads();                            // drains gload + orders LDS
        const size_t gpix = (size_t)n * HW + h * WW;
        const int ob_lo = blockIdx.y * 4;
        const int ob_hi = (ob_lo + 4 < NOB) ? ob_lo + 4 : NOB;

        for (int ob = ob_lo; ob < ob_hi; ++ob) {
            const int obase = ob * 64 + wv * 16;
            if (obase >= 432) continue;

            v4f acc[6];
            #pragma unroll
            for (int i = 0; i < 6; ++i) acc[i] = (v4f){0.f, 0.f, 0.f, 0.f};

            #pragma unroll
            for (int tap = 0; tap < 9; ++tap) {
                const int ty = tap / 3, tx = tap - ty * 3;
                #pragma unroll
                for (int kf = 0; kf < 2; ++kf) {
                    v8s bw = *(const v8s*)&wp[((((size_t)tap * NKF + kf) * NOG + (ob * 4 + wv)) * 64 + ln) * 8];
                    #pragma unroll
                    for (int fm = 0; fm < 6; ++fm) {
                        int c = fm * 16 + l15 + tx;
                        v8s a = *(const v8s*)&L[(ty * COLS + c) * 64 + (((kf * 4 + lg) ^ (c & 7)) * 8)];
                        acc[fm] = __builtin_amdgcn_mfma_f32_16x16x32_bf16(bw, a, acc[fm], 0, 0, 0);
                    }
                }
            }

            float bv[4];
            #pragma unroll
            for (int r = 0; r < 4; ++r) bv[r] = bias[obase + lg * 4 + r];

            if (obase < 288) {
                const int pr = (obase + lg * 4) >> 1;
                #pragma unroll
                for (int fm = 0; fm < 6; ++fm) {
                    const size_t pix = gpix + fm * 16 + l15;
                    u32 v0 = (u32)f2bf(acc[fm][0] + bv[0]) | ((u32)f2bf(acc[fm][1] + bv[1]) << 16);
                    u32 v1 = (u32)f2bf(acc[fm][2] + bv[2]) | ((u32)f2bf(acc[fm][3] + bv[3]) << 16);
                    pairT[(size_t)pr * NPIX + pix]       = v0;
                    pairT[(size_t)(pr + 1) * NPIX + pix] = v1;
                }
            } else {
                #pragma unroll
                for (int fm = 0; fm < 6; ++fm) {
                    const size_t pix = gpix + fm * 16 + l15;
                    #pragma unroll
                    for (int r = 0; r < 4; ++r) {
                        int mch = obase + lg * 4 + r - 288;
                        maskT[(size_t)mch * NPIX + pix] = f2bf(acc[fm][r] + bv[r]);
                    }
                }
            }
        }
    }
}

// ---------------------------------------------------------------------------
// Fused DCN sample+GEMM. 16-px x 3-set blocks (192 thr, 3 waves), grid
// 2304 = 8 XCD x 288 -> 9 blocks/CU even. In-block K reduce via 8KB LDS.
// (R13/R15: ~47.5us, VALU 57%, FETCH 21.7MB -- proven config, unchanged.)
// ---------------------------------------------------------------------------
__global__ __launch_bounds__(192) void dcn_fused(
    const u16* __restrict__ xT,     // [16][NPIX][8] bf16
    const float* __restrict__ f1,
    const float* __restrict__ f2,
    const u32*  __restrict__ pairT, // [144][NPIX] raw bf16 offset pairs
    const u16*  __restrict__ maskT, // [144][NPIX] raw bf16 mask
    const u16*  __restrict__ wdf,   // [36][4][64][8] bf16 fragment-major
    const float* __restrict__ bdcn,
    float* __restrict__ y)          // [N,64,H,W] fp32
{
    __shared__ __align__(16) v4f R[2][4][64];    // 8KB: sets 1,2 partials

    const int t    = threadIdx.x;                  // 0..191
    const int xb   = blockIdx.x;                   // 0..2303
    const int xw   = (xb & 7) * 288 + (xb >> 3);   // XCD-contiguous tile id
    const int p0   = xw * 16;
    const int ks   = t >> 6;                       // K-split set 0..2
    const int ln   = t & 63;
    const int l15  = ln & 15;
    const int lg   = ln >> 4;
    const int n    = p0 / HW;
    const int rem0 = p0 - n * HW;
    const int p    = p0 + l15;              // this thread's sampling pixel
    const int rem  = rem0 + l15;
    const int h    = rem / WW;
    const int w    = rem - h * WW;

    const char* pTc = (const char*)pairT;
    const char* mTc = (const char*)maskT;
    const char* xTc = (const char*)xT;
    const u32 p4   = (u32)p << 2;
    const u32 p2   = (u32)p << 1;
    const u32 nb16 = (u32)(n * HW) << 4;           // xT image base, 16B/pixel

    // flows + grid bases hoisted (f?yh = flow_y + h, f?xw = flow_x + w)
    const float f1yh = f1[(size_t)(n * 2 + 1) * HW + rem] + (float)h;
    const float f1xw = f1[(size_t)(n * 2 + 0) * HW + rem] + (float)w;
    const float f2yh = f2[(size_t)(n * 2 + 1) * HW + rem] + (float)h;
    const float f2xw = f2[(size_t)(n * 2 + 0) * HW + rem] + (float)w;

    auto scal = [&](int sl, u32& yx, float& mr) {
        yx = *(const u32*)(pTc + ((u32)sl * (u32)(NPIX * 4) + p4));
        mr = bf2f(*(const u16*)(mTc + ((u32)sl * (u32)(NPIX * 2) + p2)));
    };

    // coords: bilinear weights (mask folded) + issue 4 gathers
    auto coords = [&](int sl, u32 yx, float mr,
                      uint4& q00, uint4& q01, uint4& q10, uint4& q11,
                      float& w00, float& w01, float& w10, float& w11) {
        const int g  = (sl * 57) >> 9;            // sl/9 exact for sl<144
        const int kt = sl - 9 * g;
        const int ky = (kt * 11) >> 5;            // kt/3 for kt<9
        const int kx = kt - 3 * ky;
        const float fy = (g < 8) ? f1yh : f2yh;
        const float fx = (g < 8) ? f1xw : f2xw;
        const float py  = 10.0f * ftanh(lo_bf(yx)) + (fy + (float)(ky - 1));
        const float pxx = 10.0f * ftanh(hi_bf(yx)) + (fx + (float)(kx - 1));
        const float m   = fsigm(mr);

        const float y0f = floorf(py), x0f = floorf(pxx);
        const int   iy0 = (int)y0f,   ix0 = (int)x0f;
        const float wy = py - y0f, wx = pxx - x0f;
        const bool v0y = ((unsigned)iy0 < HH);
        const bool v1y = ((unsigned)(iy0 + 1) < HH);
        const bool v0x = ((unsigned)ix0 < WW);
        const bool v1x = ((unsigned)(ix0 + 1) < WW);
        const float wy0m = (1.0f - wy) * m, wy1m = wy * m;
        w00 = (v0y && v0x) ? wy0m * (1.0f - wx) : 0.0f;
        w01 = (v0y && v1x) ? wy0m * wx          : 0.0f;
        w10 = (v1y && v0x) ? wy1m * (1.0f - wx) : 0.0f;
        w11 = (v1y && v1x) ? wy1m * wx          : 0.0f;

        const int iy0c = min(max(iy0, 0), HH - 1);
        const int iy1c = min(max(iy0 + 1, 0), HH - 1);
        const int ix0c = min(max(ix0, 0), WW - 1);
        const int ix1c = min(max(ix0 + 1, 0), WW - 1);
        const u32 gof = (u32)g * (u32)(NPIX * 16) + nb16;
        const u32 r0  = gof + (u32)iy0c * (u32)(WW * 16);
        const u32 r1  = gof + (u32)iy1c * (u32)(WW * 16);
        const u32 c0  = (u32)ix0c << 4;
        const u32 c1  = (u32)ix1c << 4;
        q00 = *(const uint4*)(xTc + (r0 + c0));
        q01 = *(const uint4*)(xTc + (r0 + c1));
        q10 = *(const uint4*)(xTc + (r1 + c0));
        q11 = *(const uint4*)(xTc + (r1 + c1));
    };

    auto blend = [&](const uint4& q00, const uint4& q01,
                     const uint4& q10, const uint4& q11,
                     float w00, float w01, float w10, float w11) -> v8s {
        u32 pv0 = cvtpk(
            w00*lo_bf(q00.x) + w01*lo_bf(q01.x) + w10*lo_bf(q10.x) + w11*lo_bf(q11.x),
            w00*hi_bf(q00.x) + w01*hi_bf(q01.x) + w10*hi_bf(q10.x) + w11*hi_bf(q11.x));
        u32 pv1 = cvtpk(
            w00*lo_bf(q00.y) + w01*lo_bf(q01.y) + w10*lo_bf(q10.y) + w11*lo_bf(q11.y),
            w00*hi_bf(q00.y) + w01*hi_bf(q01.y) + w10*hi_bf(q10.y) + w11*hi_bf(q11.y));
        u32 pv2 = cvtpk(
            w00*lo_bf(q00.z) + w01*lo_bf(q01.z) + w10*lo_bf(q10.z) + w11*lo_bf(q11.z),
            w00*hi_bf(q00.z) + w01*hi_bf(q01.z) + w10*hi_bf(q10.z) + w11*hi_bf(q11.z));
        u32 pv3 = cvtpk(
            w00*lo_bf(q00.w) + w01*lo_bf(q01.w) + w10*lo_bf(q10.w) + w11*lo_bf(q11.w),
            w00*hi_bf(q00.w) + w01*hi_bf(q01.w) + w10*hi_bf(q10.w) + w11*hi_bf(q11.w));
        return u4_to_v8s(make_uint4(pv0, pv1, pv2, pv3));
    };

    v4f acc[4];
    #pragma unroll
    for (int i = 0; i < 4; ++i) acc[i] = (v4f){0.f, 0.f, 0.f, 0.f};

    const int cc0 = ks * 12;
    const int sb  = cc0 * 4 + lg;           // slot of sample i = sb + 4*i
    const char* wb = (const char*)wdf + ((u32)cc0 << 12) + ((u32)ln << 4);

    // ---- pipeline state (named, no runtime-indexed arrays) ----
    uint4 qA00, qA01, qA10, qA11;  float wA00, wA01, wA10, wA11;
    uint4 qB00, qB01, qB10, qB11;  float wB00, wB01, wB10, wB11;
    u32 yxN; float mrN;

    {   // prologue: fill A (sample 0), B (sample 1); preload scalars for 2
        u32 yx; float mr;
        scal(sb, yx, mr);
        coords(sb, yx, mr, qA00, qA01, qA10, qA11, wA00, wA01, wA10, wA11);
        scal(sb + 4, yx, mr);
        coords(sb + 4, yx, mr, qB00, qB01, qB10, qB11, wB00, wB01, wB10, wB11);
        scal(sb + 8, yxN, mrN);
    }

    #pragma unroll 1
    for (int j = 0; j < 12; j += 2) {
        {   // EVEN: consume A (sample j); refill A with sample j+2
            const char* wj = wb + ((u32)j << 12);
            v8s aW0 = *(const v8s*)(wj);
            v8s aW1 = *(const v8s*)(wj + 1024);
            v8s aW2 = *(const v8s*)(wj + 2048);
            v8s aW3 = *(const v8s*)(wj + 3072);
            v8s bP = blend(qA00, qA01, qA10, qA11, wA00, wA01, wA10, wA11);
            acc[0] = __builtin_amdgcn_mfma_f32_16x16x32_bf16(bP, aW0, acc[0], 0, 0, 0);
            acc[1] = __builtin_amdgcn_mfma_f32_16x16x32_bf16(bP, aW1, acc[1], 0, 0, 0);
            acc[2] = __builtin_amdgcn_mfma_f32_16x16x32_bf16(bP, aW2, acc[2], 0, 0, 0);
            acc[3] = __builtin_amdgcn_mfma_f32_16x16x32_bf16(bP, aW3, acc[3], 0, 0, 0);
            if (j + 2 < 12)
                coords(sb + (j + 2) * 4, yxN, mrN,
                       qA00, qA01, qA10, qA11, wA00, wA01, wA10, wA11);
            if (j + 3 < 12) scal(sb + (j + 3) * 4, yxN, mrN);
        }
        {   // ODD: consume B (sample j+1); refill B with sample j+3
            const char* wj = wb + ((u32)(j + 1) << 12);
            v8s aW0 = *(const v8s*)(wj);
            v8s aW1 = *(const v8s*)(wj + 1024);
            v8s aW2 = *(const v8s*)(wj + 2048);
            v8s aW3 = *(const v8s*)(wj + 3072);
            v8s bP = blend(qB00, qB01, qB10, qB11, wB00, wB01, wB10, wB11);
            acc[0] = __builtin_amdgcn_mfma_f32_16x16x32_bf16(bP, aW0, acc[0], 0, 0, 0);
            acc[1] = __builtin_amdgcn_mfma_f32_16x16x32_bf16(bP, aW1, acc[1], 0, 0, 0);
            acc[2] = __builtin_amdgcn_mfma_f32_16x16x32_bf16(bP, aW2, acc[2], 0, 0, 0);
            acc[3] = __builtin_amdgcn_mfma_f32_16x16x32_bf16(bP, aW3, acc[3], 0, 0, 0);
            if (j + 3 < 12)
                coords(sb + (j + 3) * 4, yxN, mrN,
                       qB00, qB01, qB10, qB11, wB00, wB01, wB10, wB11);
            if (j + 4 < 12) scal(sb + (j + 4) * 4, yxN, mrN);
        }
    }

    // ---- in-block K reduction: sets 1,2 -> LDS; set 0 sums + writes y ----
    if (ks > 0) {
        #pragma unroll
        for (int m = 0; m < 4; ++m) R[ks - 1][m][ln] = acc[m];
    }
    __syncthreads();
    if (ks == 0) {
        #pragma unroll
        for (int m = 0; m < 4; ++m) {
            v4f s = acc[m];
            v4f r1 = R[0][m][ln];
            v4f r2 = R[1][m][ln];
            const int o = m * 16 + l15;
            const float bd = bdcn[o];
            const size_t idx = (size_t)(n * C_OUT + o) * HW + rem0 + lg * 4;
            *(float4*)&y[idx] = make_float4(s[0] + r1[0] + r2[0] + bd,
                                            s[1] + r1[1] + r2[1] + bd,
                                            s[2] + r1[2] + r2[2] + bd,
                                            s[3] + r1[3] + r2[3] + bd);
        }
    }
}

// ---------------------------------------------------------------------------
extern "C" void kernel_launch(void* const* d_in, const int* in_sizes, int n_in,
                              void* d_out, int out_size, void* d_ws, size_t ws_size,
                              hipStream_t stream) {
    const float* x  = (const float*)d_in[0];
    const float* ef = (const float*)d_in[1];
    const float* f1 = (const float*)d_in[2];
    const float* f2 = (const float*)d_in[3];
    const float* w0 = (const float*)d_in[4];
    const float* b0 = (const float*)d_in[5];
    const float* w1 = (const float*)d_in[6];
    const float* b1 = (const float*)d_in[7];
    const float* w2 = (const float*)d_in[8];
    const float* b2 = (const float*)d_in[9];
    const float* w3 = (const float*)d_in[10];
    const float* b3 = (const float*)d_in[11];
    const float* wd = (const float*)d_in[12];
    const float* bd = (const float*)d_in[13];
    float* y = (float*)d_out;
    char* wsb = (char*)d_ws;

    // Workspace (bytes), 16B-aligned; total ~75.4 MB + 512B zero page.
    u16* catT  = (u16*)(wsb + 0);          // 18,874,368
    u16* h0T   = (u16*)(wsb + 18874368);   //  4,718,592
    u16* h1T   = (u16*)(wsb + 23592960);   //  4,718,592
    u16* h2T   = (u16*)(wsb + 28311552);   //  4,718,592
    u32* pairT = (u32*)(wsb + 33030144);   // 21,233,664
    u16* maskT = (u16*)(wsb + 54263808);   // 10,616,832
    u16* w0p   = (u16*)(wsb + 64880640);   //    294,912
    u16* w1p   = (u16*)(wsb + 65175552);   //     73,728
    u16* w2p   = (u16*)(wsb + 65249280);   //     73,728
    u16* w3p   = (u16*)(wsb + 65323008);   //    516,096
    u16* wdf   = (u16*)(wsb + 65839104);   //    147,456
    u16* xT    = (u16*)(wsb + 65986560);   //  9,437,184 -> ends 75,423,744
    char* zp   = (wsb + 75423744);         //        512 (zero page)

    // one fused prep dispatch: catT (2304) + xT (1152) + pack (2160) = 5616
    prep_all<<<dim3(5616), 256, 0, stream>>>(
        ef, f1, f2, x, catT, xT,
        w0, w0p, w1, w1p, w2, w2p, w3, w3p, wd, wdf, (uint4*)zp);

    conv_mfma<256, 4, 64, true,  false, 1><<<dim3(768), 256, 0, stream>>>(
        catT, w0p, b0, 64, h0T, nullptr, nullptr, zp);
    conv_mfma< 64, 1, 64, true,  false, 1><<<dim3(768), 256, 0, stream>>>(
        h0T, w1p, b1, 64, h1T, nullptr, nullptr, zp);
    conv_mfma< 64, 1, 64, true,  false, 1><<<dim3(768), 256, 0, stream>>>(
        h1T, w2p, b2, 64, h2T, nullptr, nullptr, zp);
    conv_mfma< 64, 1, 448, false, true, 7><<<dim3(NB * HH, 2), 256, 0, stream>>>(
        h2T, w3p, b3, 432, nullptr, pairT, maskT, zp);

    dcn_fused<<<dim3(NPIX / 16), 192, 0, stream>>>(
        xT, f1, f2, pairT, maskT, wdf, bd, y);
}